// Round 5
// baseline (588.177 us; speedup 1.0000x reference)
//
#include <hip/hip_runtime.h>

typedef unsigned short u16;
typedef __attribute__((ext_vector_type(8))) short bf16x8;
typedef __attribute__((ext_vector_type(4))) float f32x4;

#define L_ 512
#define D_ 128
#define LL_ (512*512)
#define LP_ 136   // LDS pitch for 128-wide rows (16B-aligned)
#define TP_ 72    // LDS pitch for 64-wide rows

// ---- workspace layouts (u16 elements) ----
// v2 (with precomputed zn): wt | bias2 | zn | a_t | b_tt | k_t  = 268.6 MB
#define WT_OFF 0
#define B2_OFF 98304            // 768 f32 = 1536 u16
#define ZN_OFF (B2_OFF + 1536)
#define AT2_OFF (ZN_OFF + 128*LL_)
#define BT2_OFF (AT2_OFF + 128*LL_)
#define KT2_OFF (BT2_OFF + 128*LL_)
#define WS2_NEED_BYTES ((size_t)(KT2_OFF + 128*LL_) * 2)
// v1 fallback (round-3 layout): wt | bias2 | a_t | b_tt | k_t = 192 MB
#define AT1_OFF (B2_OFF + 1536)
#define BT1_OFF (AT1_OFF + 128*LL_)
#define KT1_OFF (BT1_OFF + 128*LL_)

union U16x8 { uint4 u4; bf16x8 v; u16 s[8]; };
union U16x4 { ushort4 v; u16 s[4]; };

__device__ __forceinline__ u16 f2bf(float f){
  union { float f; unsigned int i; } w; w.f = f;
  unsigned int r = w.i + 0x7FFFu + ((w.i >> 16) & 1u);  // RNE
  return (u16)(r >> 16);
}
__device__ __forceinline__ float sigm(float x){
  return 1.0f / (1.0f + __expf(-x));
}

// prep: wt[w][n][k] = W_w[k][n] * lnscale[k] (bf16), and
// bias2[w][n] = b_w[n] + sum_k lnbias[k] * W_w[k][n] (f32).
__global__ __launch_bounds__(256) void conv_kernel(
    const float* __restrict__ Wga, const float* __restrict__ Wla,
    const float* __restrict__ Wgb, const float* __restrict__ Wlb,
    const float* __restrict__ Wgo, const float* __restrict__ Wlo,
    const float* __restrict__ lnw, const float* __restrict__ lnb,
    const float* __restrict__ onw, const float* __restrict__ onb,
    const float* __restrict__ bga, const float* __restrict__ bla,
    const float* __restrict__ bgb, const float* __restrict__ blb,
    const float* __restrict__ bgo, const float* __restrict__ blo,
    u16* __restrict__ wt, float* __restrict__ bias2)
{
  if (blockIdx.x < 384){
    int idx = blockIdx.x*256 + threadIdx.x;            // 0..98303
    int w = idx >> 14, rem = idx & 16383, n = rem >> 7, k = rem & 127;
    const float* src;
    switch (w){
      case 0: src = Wga; break; case 1: src = Wla; break; case 2: src = Wgb; break;
      case 3: src = Wlb; break; case 4: src = Wgo; break; default: src = Wlo;
    }
    float sc = (w == 5) ? onw[k] : lnw[k];
    wt[idx] = f2bf(src[k*128 + n] * sc);
  } else {
    int j = (blockIdx.x - 384)*256 + threadIdx.x;      // 0..767
    int w = j >> 7, n = j & 127;
    const float* src; const float* bs;
    switch (w){
      case 0: src = Wga; bs = bga; break; case 1: src = Wla; bs = bla; break;
      case 2: src = Wgb; bs = bgb; break; case 3: src = Wlb; bs = blb; break;
      case 4: src = Wgo; bs = bgo; break; default: src = Wlo; bs = blo;
    }
    const float* lb = (w == 5) ? onb : lnb;
    float acc = bs[n];
    for (int k = 0; k < 128; ++k) acc += lb[k] * src[k*128 + n];
    bias2[j] = acc;
  }
}

// stageZ: zn[pos][c] = (z[pos][c] - mu) * rstd   (bf16), computed ONCE.
__global__ __launch_bounds__(256) void stageZ_kernel(
    const float* __restrict__ z, u16* __restrict__ zn_g)
{
  const int t = threadIdx.x, r = t >> 1, h = t & 1;
  const int row = blockIdx.x*128 + r;
  const float* zrow = z + (long)row*D_ + h*64;
  float raw[64];
  float sum = 0.f, sq = 0.f;
#pragma unroll
  for (int q = 0; q < 16; ++q){
    float4 v = *(const float4*)(zrow + q*4);
    raw[q*4+0] = v.x; raw[q*4+1] = v.y; raw[q*4+2] = v.z; raw[q*4+3] = v.w;
    sum += v.x + v.y + v.z + v.w;
    sq  += v.x*v.x + v.y*v.y + v.z*v.z + v.w*v.w;
  }
  sum += __shfl_xor(sum, 1, 64);
  sq  += __shfl_xor(sq , 1, 64);
  float mu = sum * (1.f/128.f);
  float rstd = rsqrtf(sq*(1.f/128.f) - mu*mu + 1e-5f);
  u16* orow = zn_g + (long)row*D_ + h*64;
#pragma unroll
  for (int q = 0; q < 8; ++q){
    U16x8 o;
#pragma unroll
    for (int e = 0; e < 8; ++e)
      o.s[e] = f2bf((raw[q*8+e] - mu)*rstd);
    *(uint4*)(orow + q*8) = o.u4;
  }
}

// gemm over pitched LDS (LP_)
__device__ __forceinline__ void gemm128(const u16* znlds, const u16* __restrict__ wtm,
                                        int wm, int wn, int quad, int l16, f32x4 acc[4][4])
{
  bf16x8 bf[4][4];
#pragma unroll
  for (int nt = 0; nt < 4; ++nt){
    int n = wn*64 + nt*16 + l16;
#pragma unroll
    for (int kc = 0; kc < 4; ++kc){
      U16x8 u; u.u4 = *(const uint4*)(wtm + n*128 + kc*32 + quad*8);
      bf[nt][kc] = u.v;
    }
  }
#pragma unroll
  for (int mt = 0; mt < 4; ++mt){
    int row = wm*64 + mt*16 + l16;
    bf16x8 af[4];
#pragma unroll
    for (int kc = 0; kc < 4; ++kc)
      af[kc] = *(const bf16x8*)(znlds + row*LP_ + kc*32 + quad*8);
#pragma unroll
    for (int nt = 0; nt < 4; ++nt)
#pragma unroll
      for (int kc = 0; kc < 4; ++kc)
        acc[mt][nt] = __builtin_amdgcn_mfma_f32_16x16x32_bf16(af[kc], bf[nt][kc], acc[mt][nt], 0, 0, 0);
  }
}

// gemm over XOR-swizzled linear LDS (pitch 128, chunk^=(row&7))
__device__ __forceinline__ void gemm128s(const u16* znS, const u16* __restrict__ wtm,
                                         int wm, int wn, int quad, int l16, f32x4 acc[4][4])
{
  bf16x8 bf[4][4];
#pragma unroll
  for (int nt = 0; nt < 4; ++nt){
    int n = wn*64 + nt*16 + l16;
#pragma unroll
    for (int kc = 0; kc < 4; ++kc){
      U16x8 u; u.u4 = *(const uint4*)(wtm + n*128 + kc*32 + quad*8);
      bf[nt][kc] = u.v;
    }
  }
  const int r7 = l16 & 7;
#pragma unroll
  for (int mt = 0; mt < 4; ++mt){
    int row = wm*64 + mt*16 + l16;
    bf16x8 af[4];
#pragma unroll
    for (int kc = 0; kc < 4; ++kc)
      af[kc] = *(const bf16x8*)(znS + row*128 + (((kc*4 + quad) ^ r7) << 3));
#pragma unroll
    for (int nt = 0; nt < 4; ++nt)
#pragma unroll
      for (int kc = 0; kc < 4; ++kc)
        acc[mt][nt] = __builtin_amdgcn_mfma_f32_16x16x32_bf16(af[kc], bf[nt][kc], acc[mt][nt], 0, 0, 0);
  }
}

__device__ __forceinline__ void gemm64(const u16* alds, const u16* __restrict__ wtm,
                                       int wm, int wn, int quad, int l16, f32x4 acc[2][4])
{
  bf16x8 bf[4][4];
#pragma unroll
  for (int nt = 0; nt < 4; ++nt){
    int n = wn*64 + nt*16 + l16;
#pragma unroll
    for (int kc = 0; kc < 4; ++kc){
      U16x8 u; u.u4 = *(const uint4*)(wtm + n*128 + kc*32 + quad*8);
      bf[nt][kc] = u.v;
    }
  }
#pragma unroll
  for (int mt = 0; mt < 2; ++mt){
    int row = wm*32 + mt*16 + l16;
    bf16x8 af[4];
#pragma unroll
    for (int kc = 0; kc < 4; ++kc)
      af[kc] = *(const bf16x8*)(alds + row*LP_ + kc*32 + quad*8);
#pragma unroll
    for (int nt = 0; nt < 4; ++nt)
#pragma unroll
      for (int kc = 0; kc < 4; ++kc)
        acc[mt][nt] = __builtin_amdgcn_mfma_f32_16x16x32_bf16(af[kc], bf[nt][kc], acc[mt][nt], 0, 0, 0);
  }
}

// 64-row gemm over XOR-swizzled linear LDS (pitch 128)
__device__ __forceinline__ void gemm64s(const u16* aS, const u16* __restrict__ wtm,
                                        int wm, int wn, int quad, int l16, f32x4 acc[2][4])
{
  bf16x8 bf[4][4];
#pragma unroll
  for (int nt = 0; nt < 4; ++nt){
    int n = wn*64 + nt*16 + l16;
#pragma unroll
    for (int kc = 0; kc < 4; ++kc){
      U16x8 u; u.u4 = *(const uint4*)(wtm + n*128 + kc*32 + quad*8);
      bf[nt][kc] = u.v;
    }
  }
  const int r7 = l16 & 7;
#pragma unroll
  for (int mt = 0; mt < 2; ++mt){
    int row = wm*32 + mt*16 + l16;
    bf16x8 af[4];
#pragma unroll
    for (int kc = 0; kc < 4; ++kc)
      af[kc] = *(const bf16x8*)(aS + row*128 + (((kc*4 + quad) ^ r7) << 3));
#pragma unroll
    for (int nt = 0; nt < 4; ++nt)
#pragma unroll
      for (int kc = 0; kc < 4; ++kc)
        acc[mt][nt] = __builtin_amdgcn_mfma_f32_16x16x32_bf16(af[kc], bf[nt][kc], acc[mt][nt], 0, 0, 0);
  }
}

// ---------- v2 stageA: 2 tiles/block, double-buffered prefetch staging ----------
__global__ __launch_bounds__(256) void stageA2_kernel(
    const u16* __restrict__ zn_g, const u16* __restrict__ wt,
    const float* __restrict__ bias2,
    u16* __restrict__ a_t, u16* __restrict__ b_tt)
{
  __shared__ __align__(16) u16 znS[2][128*128];   // 64 KiB; trh aliases znS[cur]

  const int bid = blockIdx.x;            // 2048 blocks
  const int type = bid >> 10;
  const int tile10 = bid & 1023;
  const int outer = tile10 >> 1;         // i (type0) or j (type1)
  const int sp = (tile10 & 1)*2;         // seg pair base

  const int t = threadIdx.x;
  const int r = t >> 1, h = t & 1;
  const int lane = t & 63, wave = t >> 6;
  const int quad = lane >> 4, l16 = lane & 15;
  const int wm = wave & 1, wn = wave >> 1;
  const int lr = lane >> 4, lc = lane & 15;
  const int r7s = (wave*4 + lr) & 7;
  const int cgx = lc ^ r7s;              // pre-swizzled source chunk

  // stage zn tile seg into buffer b: LDS[row][cl] = zn_g[pos(row)][cl ^ (row&7)]
  auto stage = [&](int b, int seg){
#pragma unroll
    for (int q = 0; q < 8; ++q){
      int row = q*16 + wave*4 + lr;
      int gpos = (type == 0) ? (outer*L_ + seg*128 + row) : ((seg*128 + row)*L_ + outer);
      __builtin_amdgcn_global_load_lds(
          (const __attribute__((address_space(1))) void*)(zn_g + (long)gpos*D_ + cgx*8),
          (__attribute__((address_space(3))) void*)(&znS[b][(q*16 + wave*4)*128]),
          16, 0, 0);
    }
  };

  const u16* wg   = wt + (type ? 2 : 0)*16384;
  const u16* wl   = wt + (type ? 3 : 1)*16384;
  const float* bgp = bias2 + (type ? 2 : 0)*128;
  const float* blp = bias2 + (type ? 3 : 1)*128;
  const f32x4 z4 = {0.f, 0.f, 0.f, 0.f};
  u16* dst = type ? b_tt : a_t;

  stage(0, sp);
  for (int it2 = 0; it2 < 2; ++it2){
    const int seg = sp + it2;
    if (it2 == 0){
      stage(1, sp + 1);                                  // prefetch tile1
      asm volatile("s_waitcnt vmcnt(8)" ::: "memory");   // tile0 resident
    } else {
      asm volatile("s_waitcnt vmcnt(0)" ::: "memory");
    }
    __builtin_amdgcn_s_barrier();
    asm volatile("" ::: "memory");

    const u16* zn = &znS[it2][0];
    f32x4 accG[4][4], accL[4][4];
#pragma unroll
    for (int mt = 0; mt < 4; ++mt)
#pragma unroll
      for (int nt = 0; nt < 4; ++nt){ accG[mt][nt] = z4; accL[mt][nt] = z4; }

    gemm128s(zn, wg, wm, wn, quad, l16, accG);
#pragma unroll
    for (int nt = 0; nt < 4; ++nt){
      float bb = bgp[wn*64 + nt*16 + l16];
#pragma unroll
      for (int mt = 0; mt < 4; ++mt)
#pragma unroll
        for (int e = 0; e < 4; ++e)
          accG[mt][nt][e] = sigm(accG[mt][nt][e] + bb);
    }
    gemm128s(zn, wl, wm, wn, quad, l16, accL);
#pragma unroll
    for (int nt = 0; nt < 4; ++nt){
      float bb = blp[wn*64 + nt*16 + l16];
#pragma unroll
      for (int mt = 0; mt < 4; ++mt)
#pragma unroll
        for (int e = 0; e < 4; ++e)
          accG[mt][nt][e] *= (accL[mt][nt][e] + bb);   // gated product in accG
    }

    __syncthreads();   // gemm reads of znS[it2] done; reuse it as trh

    u16* trh = &znS[it2][0];
    const int base = outer*L_ + seg*128;
#pragma unroll
    for (int pass = 0; pass < 2; ++pass){
      if (wm == pass){
#pragma unroll
        for (int nt = 0; nt < 4; ++nt){
          int gcol = wn*64 + nt*16 + l16;
#pragma unroll
          for (int mt = 0; mt < 4; ++mt){
            U16x4 pk;
#pragma unroll
            for (int e = 0; e < 4; ++e)
              pk.s[e] = f2bf(accG[mt][nt][e]);
            *(ushort4*)(trh + gcol*TP_ + mt*16 + quad*4) = pk.v;
          }
        }
      }
      __syncthreads();
#pragma unroll
      for (int q = 0; q < 4; ++q){
        uint4 v = *(const uint4*)(trh + r*TP_ + h*32 + q*8);
        *(uint4*)(dst + r*LL_ + base + pass*64 + h*32 + q*8) = v;
      }
      __syncthreads();
    }
  }
}

// ---------- v1 stageA (fallback, LN inline) ----------
__global__ __launch_bounds__(256) void stageA_kernel(
    const float* __restrict__ z, const u16* __restrict__ wt,
    const float* __restrict__ bias2,
    u16* __restrict__ a_t, u16* __restrict__ b_tt)
{
  __shared__ __align__(16) u16 smem[128*LP_];
  u16* zn = smem;
  u16* trh = smem;

  const int bid = blockIdx.x;
  const int type = bid >> 11;
  const int tile = bid & 2047;
  const int outer = tile >> 2;
  const int seg = tile & 3;

  const int t = threadIdx.x;
  const int r = t >> 1, h = t & 1;
  const int lane = t & 63, wave = t >> 6;
  const int quad = lane >> 4, l16 = lane & 15;
  const int wm = wave & 1, wn = wave >> 1;

  {
    int gpos = (type == 0) ? (outer*L_ + seg*128 + r) : ((seg*128 + r)*L_ + outer);
    const float* zrow = z + gpos*D_ + h*64;
    float raw[64];
    float sum = 0.f, sq = 0.f;
#pragma unroll
    for (int q = 0; q < 16; ++q){
      float4 v = *(const float4*)(zrow + q*4);
      raw[q*4+0] = v.x; raw[q*4+1] = v.y; raw[q*4+2] = v.z; raw[q*4+3] = v.w;
      sum += v.x + v.y + v.z + v.w;
      sq  += v.x*v.x + v.y*v.y + v.z*v.z + v.w*v.w;
    }
    sum += __shfl_xor(sum, 1, 64);
    sq  += __shfl_xor(sq , 1, 64);
    float mu = sum * (1.f/128.f);
    float rstd = rsqrtf(sq*(1.f/128.f) - mu*mu + 1e-5f);
#pragma unroll
    for (int q = 0; q < 8; ++q){
      U16x8 o;
#pragma unroll
      for (int e = 0; e < 8; ++e)
        o.s[e] = f2bf((raw[q*8+e] - mu)*rstd);
      *(uint4*)(zn + r*LP_ + h*64 + q*8) = o.u4;
    }
  }
  __syncthreads();

  const u16* wg   = wt + (type ? 2 : 0)*16384;
  const u16* wl   = wt + (type ? 3 : 1)*16384;
  const float* bgp = bias2 + (type ? 2 : 0)*128;
  const float* blp = bias2 + (type ? 3 : 1)*128;
  const f32x4 z4 = {0.f, 0.f, 0.f, 0.f};

  f32x4 accG[4][4], accL[4][4];
#pragma unroll
  for (int mt = 0; mt < 4; ++mt)
#pragma unroll
    for (int nt = 0; nt < 4; ++nt){ accG[mt][nt] = z4; accL[mt][nt] = z4; }

  gemm128(zn, wg, wm, wn, quad, l16, accG);
#pragma unroll
  for (int nt = 0; nt < 4; ++nt){
    float bb = bgp[wn*64 + nt*16 + l16];
#pragma unroll
    for (int mt = 0; mt < 4; ++mt)
#pragma unroll
      for (int e = 0; e < 4; ++e)
        accG[mt][nt][e] = sigm(accG[mt][nt][e] + bb);
  }
  gemm128(zn, wl, wm, wn, quad, l16, accL);
#pragma unroll
  for (int nt = 0; nt < 4; ++nt){
    float bb = blp[wn*64 + nt*16 + l16];
#pragma unroll
    for (int mt = 0; mt < 4; ++mt)
#pragma unroll
      for (int e = 0; e < 4; ++e)
        accG[mt][nt][e] *= (accL[mt][nt][e] + bb);
  }

  __syncthreads();

  u16* dst = type ? b_tt : a_t;
  const int base = outer*L_ + seg*128;
#pragma unroll
  for (int pass = 0; pass < 2; ++pass){
    if (wm == pass){
#pragma unroll
      for (int nt = 0; nt < 4; ++nt){
        int gcol = wn*64 + nt*16 + l16;
#pragma unroll
        for (int mt = 0; mt < 4; ++mt){
          U16x4 pk;
#pragma unroll
          for (int e = 0; e < 4; ++e)
            pk.s[e] = f2bf(accG[mt][nt][e]);
          *(ushort4*)(trh + gcol*TP_ + mt*16 + quad*4) = pk.v;
        }
      }
    }
    __syncthreads();
#pragma unroll
    for (int q = 0; q < 4; ++q){
      uint4 v = *(const uint4*)(trh + r*TP_ + h*32 + q*8);
      *(uint4*)(dst + r*LL_ + base + pass*64 + h*32 + q*8) = v;
    }
    __syncthreads();
  }
}

// k_t[c][i][j] = sum_m a_t[c][i][m] * b_tt[c][j][m]
// double-buffered K-loop: prefetch next tile, counted vmcnt, raw barriers (r1-verified).
__global__ __launch_bounds__(256) void stageT_kernel(
    const u16* __restrict__ a_t, const u16* __restrict__ b_tt, u16* __restrict__ k_t)
{
  __shared__ __align__(16) u16 As[2][128*64];   // 32 KiB
  __shared__ __align__(16) u16 Bs[2][128*64];   // 32 KiB
  const int bid = blockIdx.x;                 // 2048 = 8 * 256
  const int lid = (bid & 7)*256 + (bid >> 3); // XCD k owns 16 whole channels
  const int c = lid >> 4, it = (lid >> 2) & 3, jt = lid & 3;
  const u16* Ab = a_t + c*LL_ + it*128*L_;
  const u16* Bb = b_tt + c*LL_ + jt*128*L_;
  const int t = threadIdx.x;
  const int lane = t & 63, wave = t >> 6;
  const int quad = lane >> 4, l16 = lane & 15;
  const int wm = wave & 1, wn = wave >> 1;
  const int sr8 = lane >> 3, scl = lane & 7;
  const int cgx = scl ^ sr8;
  const int swz = (l16 & 7) << 3;

  f32x4 acc[4][4];
  const f32x4 z4 = {0.f,0.f,0.f,0.f};
#pragma unroll
  for (int mt = 0; mt < 4; ++mt)
#pragma unroll
    for (int nt = 0; nt < 4; ++nt) acc[mt][nt] = z4;

  auto stage = [&](int b, int k0){
#pragma unroll
    for (int q = 0; q < 4; ++q){
      int row = q*32 + wave*8 + sr8;
      __builtin_amdgcn_global_load_lds(
          (const __attribute__((address_space(1))) void*)(Ab + row*L_ + k0 + cgx*8),
          (__attribute__((address_space(3))) void*)(&As[b][(q*32 + wave*8)*64]),
          16, 0, 0);
    }
#pragma unroll
    for (int q = 0; q < 4; ++q){
      int row = q*32 + wave*8 + sr8;
      __builtin_amdgcn_global_load_lds(
          (const __attribute__((address_space(1))) void*)(Bb + row*L_ + k0 + cgx*8),
          (__attribute__((address_space(3))) void*)(&Bs[b][(q*32 + wave*8)*64]),
          16, 0, 0);
    }
  };

  stage(0, 0);
  for (int kt = 0; kt < 8; ++kt){
    const int cur = kt & 1;
    if (kt < 7){
      stage(cur ^ 1, (kt + 1)*64);                       // prefetch next tile
      asm volatile("s_waitcnt vmcnt(8)" ::: "memory");   // current tile only
    } else {
      asm volatile("s_waitcnt vmcnt(0)" ::: "memory");
    }
    __builtin_amdgcn_s_barrier();
    asm volatile("" ::: "memory");
    const u16* Ac = &As[cur][0];
    const u16* Bc = &Bs[cur][0];
    bf16x8 bfr[4][2];
#pragma unroll
    for (int nt = 0; nt < 4; ++nt){
      int brow = wn*64 + nt*16 + l16;
#pragma unroll
      for (int ks = 0; ks < 2; ++ks)
        bfr[nt][ks] = *(const bf16x8*)(Bc + brow*64 + (((ks*4 + quad)*8) ^ swz));
    }
#pragma unroll
    for (int mt = 0; mt < 4; ++mt){
      int arow = wm*64 + mt*16 + l16;
      bf16x8 af[2];
#pragma unroll
      for (int ks = 0; ks < 2; ++ks)
        af[ks] = *(const bf16x8*)(Ac + arow*64 + (((ks*4 + quad)*8) ^ swz));
#pragma unroll
      for (int nt = 0; nt < 4; ++nt)
#pragma unroll
        for (int ks = 0; ks < 2; ++ks)
          acc[mt][nt] = __builtin_amdgcn_mfma_f32_16x16x32_bf16(af[ks], bfr[nt][ks], acc[mt][nt], 0, 0, 0);
    }
    asm volatile("" ::: "memory");
    __builtin_amdgcn_s_barrier();   // all reads of cur done before next overwrite
    asm volatile("" ::: "memory");
  }

#pragma unroll
  for (int mt = 0; mt < 4; ++mt)
#pragma unroll
    for (int nt = 0; nt < 4; ++nt){
      int gcol = wn*64 + nt*16 + l16;
#pragma unroll
      for (int e = 0; e < 4; ++e){
        int grow = wm*64 + mt*16 + quad*4 + e;
        k_t[c*LL_ + (it*128 + grow)*L_ + jt*128 + gcol] = f2bf(acc[mt][nt][e]);
      }
    }
}

// ---------- v2 stageC: both LDS inputs staged async via global_load_lds ----------
__global__ __launch_bounds__(256) void stageC2_kernel(
    const u16* __restrict__ k_t, const u16* __restrict__ zn_g,
    const u16* __restrict__ wt, const float* __restrict__ bias2,
    float* __restrict__ out)
{
  __shared__ __align__(16) u16 kl[128*64];    // k tile [c][j] linear (16 KB)
  __shared__ __align__(16) u16 znp[64*128];   // LN(z) rows, XOR-swizzled linear (16 KB)
  __shared__ __align__(16) u16 zn2[64*LP_];   // LN_c(k) [j][c] pitched (17 KB)
  const u16* wtgo = wt + 4*16384;
  const u16* wtlo = wt + 5*16384;
  const float* bgo2 = bias2 + 4*128;
  const float* blo2 = bias2 + 5*128;
  const int bx = blockIdx.x;
  const int pos0 = (bx >> 3)*L_ + (bx & 7)*64;
  const int t = threadIdx.x;
  const int rl4 = t >> 2, qd = t & 3;
  const int lane = t & 63, wave = t >> 6;
  const int quad = lane >> 4, l16 = lane & 15;
  const int wm = wave & 1, wn = wave >> 1;

  // issue k-tile loads: idx = q*256+t -> c = idx>>3, ch = idx&7 (16B chunks)
#pragma unroll
  for (int q = 0; q < 4; ++q){
    int base = q*256 + wave*64;
    int idx = base + lane;
    int c = idx >> 3, ch = idx & 7;
    __builtin_amdgcn_global_load_lds(
        (const __attribute__((address_space(1))) void*)(k_t + (long)c*LL_ + pos0 + ch*8),
        (__attribute__((address_space(3))) void*)(&kl[base*8]),
        16, 0, 0);
  }
  // issue zn-row loads: idx -> j = idx>>4, ch = idx&15; src chunk pre-swizzled
#pragma unroll
  for (int q = 0; q < 4; ++q){
    int base = q*256 + wave*64;
    int idx = base + lane;
    int j = idx >> 4, ch = idx & 15;
    int chx = ch ^ (j & 7);
    __builtin_amdgcn_global_load_lds(
        (const __attribute__((address_space(1))) void*)(zn_g + (long)(pos0 + j)*D_ + chx*8),
        (__attribute__((address_space(3))) void*)(&znp[base*8]),
        16, 0, 0);
  }
  asm volatile("s_waitcnt vmcnt(4)" ::: "memory");   // k-tile resident (zn in flight)
  __builtin_amdgcn_s_barrier();
  asm volatile("" ::: "memory");

  { // LN over channels of k for column j=rl4 (4 threads/column via qd)
    float sum = 0.f, sq = 0.f;
    float kv[32];
#pragma unroll
    for (int q = 0; q < 32; ++q){
      union { unsigned int i; float f; } w;
      w.i = ((unsigned int)kl[(qd*32 + q)*64 + rl4]) << 16;
      kv[q] = w.f; sum += w.f; sq += w.f*w.f;
    }
    sum += __shfl_xor(sum, 1, 64); sq += __shfl_xor(sq, 1, 64);
    sum += __shfl_xor(sum, 2, 64); sq += __shfl_xor(sq, 2, 64);
    float mu = sum*(1.f/128.f);
    float rstd = rsqrtf(sq*(1.f/128.f) - mu*mu + 1e-5f);
#pragma unroll
    for (int q = 0; q < 4; ++q){
      U16x8 o;
#pragma unroll
      for (int e = 0; e < 8; ++e)
        o.s[e] = f2bf((kv[q*8+e] - mu)*rstd);
      *(uint4*)(zn2 + rl4*LP_ + qd*32 + q*8) = o.u4;
    }
  }
  __syncthreads();   // zn2 visible; znp loads drained (vmcnt(0) implied)

  f32x4 accK[2][4], accO[2][4];
  const f32x4 z4 = {0.f,0.f,0.f,0.f};
#pragma unroll
  for (int mt = 0; mt < 2; ++mt)
#pragma unroll
    for (int nt = 0; nt < 4; ++nt){ accK[mt][nt] = z4; accO[mt][nt] = z4; }

  gemm64 (zn2, wtlo, wm, wn, quad, l16, accK);
  gemm64s(znp, wtgo, wm, wn, quad, l16, accO);

#pragma unroll
  for (int nt = 0; nt < 4; ++nt){
    int gcol = wn*64 + nt*16 + l16;
    float bo = bgo2[gcol], bl = blo2[gcol];
#pragma unroll
    for (int mt = 0; mt < 2; ++mt)
#pragma unroll
      for (int e = 0; e < 4; ++e){
        int grow = wm*32 + mt*16 + quad*4 + e;
        float s = sigm(accO[mt][nt][e] + bo);
        out[(pos0 + grow)*D_ + gcol] = s*(accK[mt][nt][e] + bl);
      }
  }
}

// ---------- v1 stageC (fallback, LN(z) inline) ----------
__global__ __launch_bounds__(256) void stageC_kernel(
    const u16* __restrict__ k_t, const float* __restrict__ z,
    const u16* __restrict__ wt, const float* __restrict__ bias2,
    float* __restrict__ out)
{
  __shared__ __align__(16) u16 zn2[64*LP_];
  __shared__ __align__(16) u16 kbuf[128*TP_];
  const u16* wtgo = wt + 4*16384;
  const u16* wtlo = wt + 5*16384;
  const float* bgo2 = bias2 + 4*128;
  const float* blo2 = bias2 + 5*128;
  const int bx = blockIdx.x;
  const int pos0 = (bx >> 3)*L_ + (bx & 7)*64;
  const int t = threadIdx.x, r = t >> 1, h = t & 1;
  const int rl4 = t >> 2, qd = t & 3;
  const int lane = t & 63, wave = t >> 6;
  const int quad = lane >> 4, l16 = lane & 15;
  const int wm = wave & 1, wn = wave >> 1;

#pragma unroll
  for (int q = 0; q < 4; ++q)
    *(uint4*)(kbuf + r*TP_ + h*32 + q*8) = *(const uint4*)(k_t + r*LL_ + pos0 + h*32 + q*8);
  __syncthreads();

  {
    float sum = 0.f, sq = 0.f;
    float kv[32];
#pragma unroll
    for (int q = 0; q < 32; ++q){
      union { unsigned int i; float f; } w;
      w.i = ((unsigned int)kbuf[(qd*32 + q)*TP_ + rl4]) << 16;
      kv[q] = w.f; sum += w.f; sq += w.f*w.f;
    }
    sum += __shfl_xor(sum, 1, 64); sq += __shfl_xor(sq, 1, 64);
    sum += __shfl_xor(sum, 2, 64); sq += __shfl_xor(sq, 2, 64);
    float mu = sum*(1.f/128.f);
    float rstd = rsqrtf(sq*(1.f/128.f) - mu*mu + 1e-5f);
#pragma unroll
    for (int q = 0; q < 4; ++q){
      U16x8 o;
#pragma unroll
      for (int e = 0; e < 8; ++e)
        o.s[e] = f2bf((kv[q*8+e] - mu)*rstd);
      *(uint4*)(zn2 + rl4*LP_ + qd*32 + q*8) = o.u4;
    }
  }
  __syncthreads();

  {
    const float* zr = z + (pos0 + rl4)*D_ + qd*32;
    float zv[32];
    float sum = 0.f, sq = 0.f;
#pragma unroll
    for (int q = 0; q < 8; ++q){
      float4 v = *(const float4*)(zr + q*4);
      zv[q*4+0] = v.x; zv[q*4+1] = v.y; zv[q*4+2] = v.z; zv[q*4+3] = v.w;
      sum += v.x + v.y + v.z + v.w;
      sq  += v.x*v.x + v.y*v.y + v.z*v.z + v.w*v.w;
    }
    sum += __shfl_xor(sum, 1, 64); sq += __shfl_xor(sq, 1, 64);
    sum += __shfl_xor(sum, 2, 64); sq += __shfl_xor(sq, 2, 64);
    float mu = sum*(1.f/128.f);
    float rstd = rsqrtf(sq*(1.f/128.f) - mu*mu + 1e-5f);
#pragma unroll
    for (int q = 0; q < 4; ++q){
      U16x8 o;
#pragma unroll
      for (int e = 0; e < 8; ++e)
        o.s[e] = f2bf((zv[q*8+e] - mu)*rstd);
      *(uint4*)(kbuf + rl4*LP_ + qd*32 + q*8) = o.u4;
    }
  }
  __syncthreads();

  f32x4 accK[2][4], accO[2][4];
  const f32x4 z4 = {0.f,0.f,0.f,0.f};
#pragma unroll
  for (int mt = 0; mt < 2; ++mt)
#pragma unroll
    for (int nt = 0; nt < 4; ++nt){ accK[mt][nt] = z4; accO[mt][nt] = z4; }

  gemm64(zn2,  wtlo, wm, wn, quad, l16, accK);
  gemm64(kbuf, wtgo, wm, wn, quad, l16, accO);

#pragma unroll
  for (int nt = 0; nt < 4; ++nt){
    int gcol = wn*64 + nt*16 + l16;
    float bo = bgo2[gcol], bl = blo2[gcol];
#pragma unroll
    for (int mt = 0; mt < 2; ++mt)
#pragma unroll
      for (int e = 0; e < 4; ++e){
        int grow = wm*32 + mt*16 + quad*4 + e;
        float s = sigm(accO[mt][nt][e] + bo);
        out[(pos0 + grow)*D_ + gcol] = s*(accK[mt][nt][e] + bl);
      }
  }
}

extern "C" void kernel_launch(void* const* d_in, const int* in_sizes, int n_in,
                              void* d_out, int out_size, void* d_ws, size_t ws_size,
                              hipStream_t stream)
{
  const float* z   = (const float*)d_in[0];
  const float* lnw = (const float*)d_in[1];
  const float* lnb = (const float*)d_in[2];
  const float* Wga = (const float*)d_in[3];
  const float* bga = (const float*)d_in[4];
  const float* Wla = (const float*)d_in[5];
  const float* bla = (const float*)d_in[6];
  const float* Wgb = (const float*)d_in[7];
  const float* bgb = (const float*)d_in[8];
  const float* Wlb = (const float*)d_in[9];
  const float* blb = (const float*)d_in[10];
  const float* onw = (const float*)d_in[11];
  const float* onb = (const float*)d_in[12];
  const float* Wgo = (const float*)d_in[13];
  const float* bgo = (const float*)d_in[14];
  const float* Wlo = (const float*)d_in[15];
  const float* blo = (const float*)d_in[16];

  u16* ws   = (u16*)d_ws;
  u16* wt   = ws + WT_OFF;
  float* b2 = (float*)(ws + B2_OFF);
  float* out = (float*)d_out;

  conv_kernel<<<387, 256, 0, stream>>>(Wga, Wla, Wgb, Wlb, Wgo, Wlo,
                                       lnw, lnb, onw, onb,
                                       bga, bla, bgb, blb, bgo, blo, wt, b2);

  if (ws_size >= WS2_NEED_BYTES){
    u16* zn_g = ws + ZN_OFF;
    u16* a_t  = ws + AT2_OFF;
    u16* b_tt = ws + BT2_OFF;
    u16* k_t  = ws + KT2_OFF;
    stageZ_kernel<<<2048, 256, 0, stream>>>(z, zn_g);
    stageA2_kernel<<<2048, 256, 0, stream>>>(zn_g, wt, b2, a_t, b_tt);
    stageT_kernel<<<2048, 256, 0, stream>>>(a_t, b_tt, k_t);
    stageC2_kernel<<<4096, 256, 0, stream>>>(k_t, zn_g, wt, b2, out);
  } else {
    u16* a_t  = ws + AT1_OFF;
    u16* b_tt = ws + BT1_OFF;
    u16* k_t  = ws + KT1_OFF;
    stageA_kernel<<<4096, 256, 0, stream>>>(z, wt, b2, a_t, b_tt);
    stageT_kernel<<<2048, 256, 0, stream>>>(a_t, b_tt, k_t);
    stageC_kernel<<<4096, 256, 0, stream>>>(k_t, z, wt, b2, out);
  }
}

// Round 6
// 526.124 us; speedup vs baseline: 1.1179x; 1.1179x over previous
//
#include <hip/hip_runtime.h>

typedef unsigned short u16;
typedef __attribute__((ext_vector_type(8))) short bf16x8;
typedef __attribute__((ext_vector_type(4))) float f32x4;

#define L_ 512
#define D_ 128
#define LL_ (512*512)
#define LP_ 136   // LDS pitch for 128-wide rows (16B-aligned)
#define TP_ 72    // LDS pitch for 64-wide rows

// ---- workspace layouts (u16 elements) ----
#define WT_OFF 0
#define B2_OFF 98304            // 768 f32 = 1536 u16
#define ZN_OFF (B2_OFF + 1536)
#define AT2_OFF (ZN_OFF + 128*LL_)
#define BT2_OFF (AT2_OFF + 128*LL_)
#define KT2_OFF (BT2_OFF + 128*LL_)
#define WS2_NEED_BYTES ((size_t)(KT2_OFF + 128*LL_) * 2)
// v1 fallback layout
#define AT1_OFF (B2_OFF + 1536)
#define BT1_OFF (AT1_OFF + 128*LL_)
#define KT1_OFF (BT1_OFF + 128*LL_)

union U16x8 { uint4 u4; bf16x8 v; u16 s[8]; };
union U16x4 { ushort4 v; u16 s[4]; };

__device__ __forceinline__ u16 f2bf(float f){
  union { float f; unsigned int i; } w; w.f = f;
  unsigned int r = w.i + 0x7FFFu + ((w.i >> 16) & 1u);  // RNE
  return (u16)(r >> 16);
}
__device__ __forceinline__ float sigm(float x){
  return 1.0f / (1.0f + __expf(-x));
}

// ---------- v2 prep: stageZ (blocks 0..2047) + weight transform (2048..2434) ----------
__global__ __launch_bounds__(256) void convZ_kernel(
    const float* __restrict__ z, u16* __restrict__ zn_g,
    const float* __restrict__ Wga, const float* __restrict__ Wla,
    const float* __restrict__ Wgb, const float* __restrict__ Wlb,
    const float* __restrict__ Wgo, const float* __restrict__ Wlo,
    const float* __restrict__ lnw, const float* __restrict__ lnb,
    const float* __restrict__ onw, const float* __restrict__ onb,
    const float* __restrict__ bga, const float* __restrict__ bla,
    const float* __restrict__ bgb, const float* __restrict__ blb,
    const float* __restrict__ bgo, const float* __restrict__ blo,
    u16* __restrict__ wt, float* __restrict__ bias2)
{
  if (blockIdx.x < 2048){
    // zn[pos][c] = (z[pos][c] - mu) * rstd  (bf16), once.
    const int t = threadIdx.x, r = t >> 1, h = t & 1;
    const int row = blockIdx.x*128 + r;
    const float* zrow = z + (long)row*D_ + h*64;
    float raw[64];
    float sum = 0.f, sq = 0.f;
#pragma unroll
    for (int q = 0; q < 16; ++q){
      float4 v = *(const float4*)(zrow + q*4);
      raw[q*4+0] = v.x; raw[q*4+1] = v.y; raw[q*4+2] = v.z; raw[q*4+3] = v.w;
      sum += v.x + v.y + v.z + v.w;
      sq  += v.x*v.x + v.y*v.y + v.z*v.z + v.w*v.w;
    }
    sum += __shfl_xor(sum, 1, 64);
    sq  += __shfl_xor(sq , 1, 64);
    float mu = sum * (1.f/128.f);
    float rstd = rsqrtf(sq*(1.f/128.f) - mu*mu + 1e-5f);
    u16* orow = zn_g + (long)row*D_ + h*64;
#pragma unroll
    for (int q = 0; q < 8; ++q){
      U16x8 o;
#pragma unroll
      for (int e = 0; e < 8; ++e)
        o.s[e] = f2bf((raw[q*8+e] - mu)*rstd);
      *(uint4*)(orow + q*8) = o.u4;
    }
    return;
  }
  int vb = blockIdx.x - 2048;
  if (vb < 384){
    int idx = vb*256 + threadIdx.x;            // 0..98303
    int w = idx >> 14, rem = idx & 16383, n = rem >> 7, k = rem & 127;
    const float* src;
    switch (w){
      case 0: src = Wga; break; case 1: src = Wla; break; case 2: src = Wgb; break;
      case 3: src = Wlb; break; case 4: src = Wgo; break; default: src = Wlo;
    }
    float sc = (w == 5) ? onw[k] : lnw[k];
    wt[idx] = f2bf(src[k*128 + n] * sc);
  } else {
    int j = (vb - 384)*256 + threadIdx.x;      // 0..767
    if (j < 768){
      int w = j >> 7, n = j & 127;
      const float* src; const float* bs;
      switch (w){
        case 0: src = Wga; bs = bga; break; case 1: src = Wla; bs = bla; break;
        case 2: src = Wgb; bs = bgb; break; case 3: src = Wlb; bs = blb; break;
        case 4: src = Wgo; bs = bgo; break; default: src = Wlo; bs = blo;
      }
      const float* lb = (w == 5) ? onb : lnb;
      float acc = bs[n];
      for (int k = 0; k < 128; ++k) acc += lb[k] * src[k*128 + n];
      bias2[j] = acc;
    }
  }
}

// ---------- v1 prep (fallback) ----------
__global__ __launch_bounds__(256) void conv_kernel(
    const float* __restrict__ Wga, const float* __restrict__ Wla,
    const float* __restrict__ Wgb, const float* __restrict__ Wlb,
    const float* __restrict__ Wgo, const float* __restrict__ Wlo,
    const float* __restrict__ lnw, const float* __restrict__ lnb,
    const float* __restrict__ onw, const float* __restrict__ onb,
    const float* __restrict__ bga, const float* __restrict__ bla,
    const float* __restrict__ bgb, const float* __restrict__ blb,
    const float* __restrict__ bgo, const float* __restrict__ blo,
    u16* __restrict__ wt, float* __restrict__ bias2)
{
  if (blockIdx.x < 384){
    int idx = blockIdx.x*256 + threadIdx.x;
    int w = idx >> 14, rem = idx & 16383, n = rem >> 7, k = rem & 127;
    const float* src;
    switch (w){
      case 0: src = Wga; break; case 1: src = Wla; break; case 2: src = Wgb; break;
      case 3: src = Wlb; break; case 4: src = Wgo; break; default: src = Wlo;
    }
    float sc = (w == 5) ? onw[k] : lnw[k];
    wt[idx] = f2bf(src[k*128 + n] * sc);
  } else {
    int j = (blockIdx.x - 384)*256 + threadIdx.x;
    int w = j >> 7, n = j & 127;
    const float* src; const float* bs;
    switch (w){
      case 0: src = Wga; bs = bga; break; case 1: src = Wla; bs = bla; break;
      case 2: src = Wgb; bs = bgb; break; case 3: src = Wlb; bs = blb; break;
      case 4: src = Wgo; bs = bgo; break; default: src = Wlo; bs = blo;
    }
    const float* lb = (w == 5) ? onb : lnb;
    float acc = bs[n];
    for (int k = 0; k < 128; ++k) acc += lb[k] * src[k*128 + n];
    bias2[j] = acc;
  }
}

// gemm over pitched LDS (LP_) — v1 fallback
__device__ __forceinline__ void gemm128(const u16* znlds, const u16* __restrict__ wtm,
                                        int wm, int wn, int quad, int l16, f32x4 acc[4][4])
{
  bf16x8 bf[4][4];
#pragma unroll
  for (int nt = 0; nt < 4; ++nt){
    int n = wn*64 + nt*16 + l16;
#pragma unroll
    for (int kc = 0; kc < 4; ++kc){
      U16x8 u; u.u4 = *(const uint4*)(wtm + n*128 + kc*32 + quad*8);
      bf[nt][kc] = u.v;
    }
  }
#pragma unroll
  for (int mt = 0; mt < 4; ++mt){
    int row = wm*64 + mt*16 + l16;
    bf16x8 af[4];
#pragma unroll
    for (int kc = 0; kc < 4; ++kc)
      af[kc] = *(const bf16x8*)(znlds + row*LP_ + kc*32 + quad*8);
#pragma unroll
    for (int nt = 0; nt < 4; ++nt)
#pragma unroll
      for (int kc = 0; kc < 4; ++kc)
        acc[mt][nt] = __builtin_amdgcn_mfma_f32_16x16x32_bf16(af[kc], bf[nt][kc], acc[mt][nt], 0, 0, 0);
  }
}

__device__ __forceinline__ void gemm64(const u16* alds, const u16* __restrict__ wtm,
                                       int wm, int wn, int quad, int l16, f32x4 acc[2][4])
{
  bf16x8 bf[4][4];
#pragma unroll
  for (int nt = 0; nt < 4; ++nt){
    int n = wn*64 + nt*16 + l16;
#pragma unroll
    for (int kc = 0; kc < 4; ++kc){
      U16x8 u; u.u4 = *(const uint4*)(wtm + n*128 + kc*32 + quad*8);
      bf[nt][kc] = u.v;
    }
  }
#pragma unroll
  for (int mt = 0; mt < 2; ++mt){
    int row = wm*32 + mt*16 + l16;
    bf16x8 af[4];
#pragma unroll
    for (int kc = 0; kc < 4; ++kc)
      af[kc] = *(const bf16x8*)(alds + row*LP_ + kc*32 + quad*8);
#pragma unroll
    for (int nt = 0; nt < 4; ++nt)
#pragma unroll
      for (int kc = 0; kc < 4; ++kc)
        acc[mt][nt] = __builtin_amdgcn_mfma_f32_16x16x32_bf16(af[kc], bf[nt][kc], acc[mt][nt], 0, 0, 0);
  }
}

// ---------- v2 stageA: fused G/L gemm per N-tile, packed bf16 results (VGPR diet) ----------
__global__ __launch_bounds__(256) void stageA2_kernel(
    const u16* __restrict__ zn_g, const u16* __restrict__ wt,
    const float* __restrict__ bias2,
    u16* __restrict__ a_t, u16* __restrict__ b_tt)
{
  __shared__ __align__(16) u16 znS[128*128];   // 32 KiB; reused as trh after gemms

  const int bid = blockIdx.x;            // 4096 blocks, one 128-tile each
  const int type = bid >> 11;
  const int tile = bid & 2047;
  const int outer = tile >> 2;
  const int seg = tile & 3;

  const int t = threadIdx.x;
  const int r = t >> 1, h = t & 1;
  const int lane = t & 63, wave = t >> 6;
  const int quad = lane >> 4, l16 = lane & 15;
  const int wm = wave & 1, wn = wave >> 1;

  { // stage zn tile: LDS[row][cl] = zn_g[pos(row)][cl ^ (row&7)] (16B chunks)
    const int lr = lane >> 4, lc = lane & 15;
    const int r7s = (wave*4 + lr) & 7;
    const int cgx = lc ^ r7s;
#pragma unroll
    for (int q = 0; q < 8; ++q){
      int row = q*16 + wave*4 + lr;
      int gpos = (type == 0) ? (outer*L_ + seg*128 + row) : ((seg*128 + row)*L_ + outer);
      __builtin_amdgcn_global_load_lds(
          (const __attribute__((address_space(1))) void*)(zn_g + (long)gpos*D_ + cgx*8),
          (__attribute__((address_space(3))) void*)(&znS[(q*16 + wave*4)*128]),
          16, 0, 0);
    }
  }
  __syncthreads();

  const u16* wg   = wt + (type ? 2 : 0)*16384;
  const u16* wl   = wt + (type ? 3 : 1)*16384;
  const float* bgp = bias2 + (type ? 2 : 0)*128;
  const float* blp = bias2 + (type ? 3 : 1)*128;
  const int r7 = l16 & 7;

  // fused per-nt: both gemms share each A-fragment; results packed to bf16 u32 pairs
  unsigned int pk[4][4][2];
#pragma unroll
  for (int nt = 0; nt < 4; ++nt){
    const int n = wn*64 + nt*16 + l16;
    bf16x8 bg[4], blw[4];
#pragma unroll
    for (int kc = 0; kc < 4; ++kc){
      U16x8 u; u.u4 = *(const uint4*)(wg + n*128 + kc*32 + quad*8); bg[kc]  = u.v;
      U16x8 v; v.u4 = *(const uint4*)(wl + n*128 + kc*32 + quad*8); blw[kc] = v.v;
    }
    f32x4 aG[4], aL[4];
#pragma unroll
    for (int mt = 0; mt < 4; ++mt){
      aG[mt] = (f32x4){0.f,0.f,0.f,0.f};
      aL[mt] = (f32x4){0.f,0.f,0.f,0.f};
    }
#pragma unroll
    for (int mt = 0; mt < 4; ++mt){
      const int row = wm*64 + mt*16 + l16;
#pragma unroll
      for (int kc = 0; kc < 4; ++kc){
        bf16x8 af = *(const bf16x8*)(znS + row*128 + (((kc*4 + quad) ^ r7) << 3));
        aG[mt] = __builtin_amdgcn_mfma_f32_16x16x32_bf16(af, bg[kc],  aG[mt], 0, 0, 0);
        aL[mt] = __builtin_amdgcn_mfma_f32_16x16x32_bf16(af, blw[kc], aL[mt], 0, 0, 0);
      }
    }
    const float bbG = bgp[n], bbL = blp[n];
#pragma unroll
    for (int mt = 0; mt < 4; ++mt){
      float v0 = sigm(aG[mt][0] + bbG) * (aL[mt][0] + bbL);
      float v1 = sigm(aG[mt][1] + bbG) * (aL[mt][1] + bbL);
      float v2 = sigm(aG[mt][2] + bbG) * (aL[mt][2] + bbL);
      float v3 = sigm(aG[mt][3] + bbG) * (aL[mt][3] + bbL);
      pk[nt][mt][0] = (unsigned)f2bf(v0) | ((unsigned)f2bf(v1) << 16);
      pk[nt][mt][1] = (unsigned)f2bf(v2) | ((unsigned)f2bf(v3) << 16);
    }
  }

  __syncthreads();   // all LDS reads of znS done; reuse as trh

  u16* trh = znS;
  u16* dst = type ? b_tt : a_t;
  const int base = outer*L_ + seg*128;
#pragma unroll
  for (int pass = 0; pass < 2; ++pass){
    if (wm == pass){
#pragma unroll
      for (int nt = 0; nt < 4; ++nt){
        int gcol = wn*64 + nt*16 + l16;
#pragma unroll
        for (int mt = 0; mt < 4; ++mt){
          uint2 w2; w2.x = pk[nt][mt][0]; w2.y = pk[nt][mt][1];
          *(uint2*)(trh + gcol*TP_ + mt*16 + quad*4) = w2;
        }
      }
    }
    __syncthreads();
#pragma unroll
    for (int q = 0; q < 4; ++q){
      uint4 v = *(const uint4*)(trh + r*TP_ + h*32 + q*8);
      *(uint4*)(dst + r*LL_ + base + pass*64 + h*32 + q*8) = v;
    }
    __syncthreads();
  }
}

// ---------- v1 stageA (fallback, LN inline) ----------
__global__ __launch_bounds__(256) void stageA_kernel(
    const float* __restrict__ z, const u16* __restrict__ wt,
    const float* __restrict__ bias2,
    u16* __restrict__ a_t, u16* __restrict__ b_tt)
{
  __shared__ __align__(16) u16 smem[128*LP_];
  u16* zn = smem;
  u16* trh = smem;

  const int bid = blockIdx.x;
  const int type = bid >> 11;
  const int tile = bid & 2047;
  const int outer = tile >> 2;
  const int seg = tile & 3;

  const int t = threadIdx.x;
  const int r = t >> 1, h = t & 1;
  const int lane = t & 63, wave = t >> 6;
  const int quad = lane >> 4, l16 = lane & 15;
  const int wm = wave & 1, wn = wave >> 1;

  {
    int gpos = (type == 0) ? (outer*L_ + seg*128 + r) : ((seg*128 + r)*L_ + outer);
    const float* zrow = z + gpos*D_ + h*64;
    float raw[64];
    float sum = 0.f, sq = 0.f;
#pragma unroll
    for (int q = 0; q < 16; ++q){
      float4 v = *(const float4*)(zrow + q*4);
      raw[q*4+0] = v.x; raw[q*4+1] = v.y; raw[q*4+2] = v.z; raw[q*4+3] = v.w;
      sum += v.x + v.y + v.z + v.w;
      sq  += v.x*v.x + v.y*v.y + v.z*v.z + v.w*v.w;
    }
    sum += __shfl_xor(sum, 1, 64);
    sq  += __shfl_xor(sq , 1, 64);
    float mu = sum * (1.f/128.f);
    float rstd = rsqrtf(sq*(1.f/128.f) - mu*mu + 1e-5f);
#pragma unroll
    for (int q = 0; q < 8; ++q){
      U16x8 o;
#pragma unroll
      for (int e = 0; e < 8; ++e)
        o.s[e] = f2bf((raw[q*8+e] - mu)*rstd);
      *(uint4*)(zn + r*LP_ + h*64 + q*8) = o.u4;
    }
  }
  __syncthreads();

  const u16* wg   = wt + (type ? 2 : 0)*16384;
  const u16* wl   = wt + (type ? 3 : 1)*16384;
  const float* bgp = bias2 + (type ? 2 : 0)*128;
  const float* blp = bias2 + (type ? 3 : 1)*128;
  const f32x4 z4 = {0.f, 0.f, 0.f, 0.f};

  f32x4 accG[4][4], accL[4][4];
#pragma unroll
  for (int mt = 0; mt < 4; ++mt)
#pragma unroll
    for (int nt = 0; nt < 4; ++nt){ accG[mt][nt] = z4; accL[mt][nt] = z4; }

  gemm128(zn, wg, wm, wn, quad, l16, accG);
#pragma unroll
  for (int nt = 0; nt < 4; ++nt){
    float bb = bgp[wn*64 + nt*16 + l16];
#pragma unroll
    for (int mt = 0; mt < 4; ++mt)
#pragma unroll
      for (int e = 0; e < 4; ++e)
        accG[mt][nt][e] = sigm(accG[mt][nt][e] + bb);
  }
  gemm128(zn, wl, wm, wn, quad, l16, accL);
#pragma unroll
  for (int nt = 0; nt < 4; ++nt){
    float bb = blp[wn*64 + nt*16 + l16];
#pragma unroll
    for (int mt = 0; mt < 4; ++mt)
#pragma unroll
      for (int e = 0; e < 4; ++e)
        accG[mt][nt][e] *= (accL[mt][nt][e] + bb);
  }

  __syncthreads();

  u16* dst = type ? b_tt : a_t;
  const int base = outer*L_ + seg*128;
#pragma unroll
  for (int pass = 0; pass < 2; ++pass){
    if (wm == pass){
#pragma unroll
      for (int nt = 0; nt < 4; ++nt){
        int gcol = wn*64 + nt*16 + l16;
#pragma unroll
        for (int mt = 0; mt < 4; ++mt){
          U16x4 pk4;
#pragma unroll
          for (int e = 0; e < 4; ++e)
            pk4.s[e] = f2bf(accG[mt][nt][e]);
          *(ushort4*)(trh + gcol*TP_ + mt*16 + quad*4) = pk4.v;
        }
      }
    }
    __syncthreads();
#pragma unroll
    for (int q = 0; q < 4; ++q){
      uint4 v = *(const uint4*)(trh + r*TP_ + h*32 + q*8);
      *(uint4*)(dst + r*LL_ + base + pass*64 + h*32 + q*8) = v;
    }
    __syncthreads();
  }
}

// k_t[c][i][j] = sum_m a_t[c][i][m] * b_tt[c][j][m]
// r4-verified: single-buffer 32 KB, global_load_lds w16 + XOR swizzle, XCD-swizzled grid.
__global__ __launch_bounds__(256) void stageT_kernel(
    const u16* __restrict__ a_t, const u16* __restrict__ b_tt, u16* __restrict__ k_t)
{
  __shared__ __align__(16) u16 As[128*64];   // 16 KiB
  __shared__ __align__(16) u16 Bs[128*64];   // 16 KiB
  const int bid = blockIdx.x;                 // 2048 = 8 * 256
  const int lid = (bid & 7)*256 + (bid >> 3); // XCD k owns 16 whole channels
  const int c = lid >> 4, it = (lid >> 2) & 3, jt = lid & 3;
  const u16* Ab = a_t + c*LL_ + it*128*L_;
  const u16* Bb = b_tt + c*LL_ + jt*128*L_;
  const int t = threadIdx.x;
  const int lane = t & 63, wave = t >> 6;
  const int quad = lane >> 4, l16 = lane & 15;
  const int wm = wave & 1, wn = wave >> 1;
  const int sr8 = lane >> 3, scl = lane & 7;
  const int cgx = scl ^ sr8;
  const int swz = (l16 & 7) << 3;

  f32x4 acc[4][4];
  const f32x4 z4 = {0.f,0.f,0.f,0.f};
#pragma unroll
  for (int mt = 0; mt < 4; ++mt)
#pragma unroll
    for (int nt = 0; nt < 4; ++nt) acc[mt][nt] = z4;

  for (int kt = 0; kt < 8; ++kt){
    const int k0 = kt*64;
#pragma unroll
    for (int q = 0; q < 4; ++q){
      int row = q*32 + wave*8 + sr8;
      __builtin_amdgcn_global_load_lds(
          (const __attribute__((address_space(1))) void*)(Ab + row*L_ + k0 + cgx*8),
          (__attribute__((address_space(3))) void*)(&As[(q*32 + wave*8)*64]),
          16, 0, 0);
    }
#pragma unroll
    for (int q = 0; q < 4; ++q){
      int row = q*32 + wave*8 + sr8;
      __builtin_amdgcn_global_load_lds(
          (const __attribute__((address_space(1))) void*)(Bb + row*L_ + k0 + cgx*8),
          (__attribute__((address_space(3))) void*)(&Bs[(q*32 + wave*8)*64]),
          16, 0, 0);
    }
    __syncthreads();
    bf16x8 bfr[4][2];
#pragma unroll
    for (int nt = 0; nt < 4; ++nt){
      int brow = wn*64 + nt*16 + l16;
#pragma unroll
      for (int ks = 0; ks < 2; ++ks)
        bfr[nt][ks] = *(const bf16x8*)(Bs + brow*64 + (((ks*4 + quad)*8) ^ swz));
    }
#pragma unroll
    for (int mt = 0; mt < 4; ++mt){
      int arow = wm*64 + mt*16 + l16;
      bf16x8 af[2];
#pragma unroll
      for (int ks = 0; ks < 2; ++ks)
        af[ks] = *(const bf16x8*)(As + arow*64 + (((ks*4 + quad)*8) ^ swz));
#pragma unroll
      for (int nt = 0; nt < 4; ++nt)
#pragma unroll
        for (int ks = 0; ks < 2; ++ks)
          acc[mt][nt] = __builtin_amdgcn_mfma_f32_16x16x32_bf16(af[ks], bfr[nt][ks], acc[mt][nt], 0, 0, 0);
    }
    __syncthreads();
  }

#pragma unroll
  for (int mt = 0; mt < 4; ++mt)
#pragma unroll
    for (int nt = 0; nt < 4; ++nt){
      int gcol = wn*64 + nt*16 + l16;
#pragma unroll
      for (int e = 0; e < 4; ++e){
        int grow = wm*64 + mt*16 + quad*4 + e;
        k_t[c*LL_ + (it*128 + grow)*L_ + jt*128 + gcol] = f2bf(acc[mt][nt][e]);
      }
    }
}

// ---------- v2 stageC: async staging + fused K/O gemms per N-tile (VGPR diet) ----------
__global__ __launch_bounds__(256) void stageC2_kernel(
    const u16* __restrict__ k_t, const u16* __restrict__ zn_g,
    const u16* __restrict__ wt, const float* __restrict__ bias2,
    float* __restrict__ out)
{
  __shared__ __align__(16) u16 kl[128*64];    // k tile [c][j] linear (16 KB)
  __shared__ __align__(16) u16 znp[64*128];   // zn rows, XOR-swizzled linear (16 KB)
  __shared__ __align__(16) u16 zn2[64*LP_];   // LN_c(k) [j][c] pitched (17 KB)
  const u16* wtgo = wt + 4*16384;
  const u16* wtlo = wt + 5*16384;
  const float* bgo2 = bias2 + 4*128;
  const float* blo2 = bias2 + 5*128;
  const int bx = blockIdx.x;
  const int pos0 = (bx >> 3)*L_ + (bx & 7)*64;
  const int t = threadIdx.x;
  const int rl4 = t >> 2, qd = t & 3;
  const int lane = t & 63, wave = t >> 6;
  const int quad = lane >> 4, l16 = lane & 15;
  const int wm = wave & 1, wn = wave >> 1;

  // issue k-tile loads: idx -> c = idx>>3, ch = idx&7 (16B chunks)
#pragma unroll
  for (int q = 0; q < 4; ++q){
    int base = q*256 + wave*64;
    int idx = base + lane;
    int c = idx >> 3, ch = idx & 7;
    __builtin_amdgcn_global_load_lds(
        (const __attribute__((address_space(1))) void*)(k_t + (long)c*LL_ + pos0 + ch*8),
        (__attribute__((address_space(3))) void*)(&kl[base*8]),
        16, 0, 0);
  }
  // issue zn-row loads: idx -> j = idx>>4, ch = idx&15; src chunk pre-swizzled
#pragma unroll
  for (int q = 0; q < 4; ++q){
    int base = q*256 + wave*64;
    int idx = base + lane;
    int j = idx >> 4, ch = idx & 15;
    int chx = ch ^ (j & 7);
    __builtin_amdgcn_global_load_lds(
        (const __attribute__((address_space(1))) void*)(zn_g + (long)(pos0 + j)*D_ + chx*8),
        (__attribute__((address_space(3))) void*)(&znp[base*8]),
        16, 0, 0);
  }
  asm volatile("s_waitcnt vmcnt(4)" ::: "memory");   // k-tile resident (zn in flight)
  __builtin_amdgcn_s_barrier();
  asm volatile("" ::: "memory");

  { // LN over channels of k for column j=rl4 (4 threads/column via qd)
    float sum = 0.f, sq = 0.f;
    float kv[32];
#pragma unroll
    for (int q = 0; q < 32; ++q){
      union { unsigned int i; float f; } w;
      w.i = ((unsigned int)kl[(qd*32 + q)*64 + rl4]) << 16;
      kv[q] = w.f; sum += w.f; sq += w.f*w.f;
    }
    sum += __shfl_xor(sum, 1, 64); sq += __shfl_xor(sq, 1, 64);
    sum += __shfl_xor(sum, 2, 64); sq += __shfl_xor(sq, 2, 64);
    float mu = sum*(1.f/128.f);
    float rstd = rsqrtf(sq*(1.f/128.f) - mu*mu + 1e-5f);
#pragma unroll
    for (int q = 0; q < 4; ++q){
      U16x8 o;
#pragma unroll
      for (int e = 0; e < 8; ++e)
        o.s[e] = f2bf((kv[q*8+e] - mu)*rstd);
      *(uint4*)(zn2 + rl4*LP_ + qd*32 + q*8) = o.u4;
    }
  }
  __syncthreads();   // zn2 visible; znp loads drained (full vmcnt drain at barrier)

  const int r7 = l16 & 7;
#pragma unroll
  for (int nt = 0; nt < 4; ++nt){
    const int gcol = wn*64 + nt*16 + l16;
    bf16x8 bk[4], bo[4];
#pragma unroll
    for (int kc = 0; kc < 4; ++kc){
      U16x8 u; u.u4 = *(const uint4*)(wtlo + gcol*128 + kc*32 + quad*8); bk[kc] = u.v;
      U16x8 v; v.u4 = *(const uint4*)(wtgo + gcol*128 + kc*32 + quad*8); bo[kc] = v.v;
    }
    f32x4 aK[2], aO[2];
#pragma unroll
    for (int mt = 0; mt < 2; ++mt){
      aK[mt] = (f32x4){0.f,0.f,0.f,0.f};
      aO[mt] = (f32x4){0.f,0.f,0.f,0.f};
    }
#pragma unroll
    for (int mt = 0; mt < 2; ++mt){
      const int row = wm*32 + mt*16 + l16;
#pragma unroll
      for (int kc = 0; kc < 4; ++kc){
        bf16x8 afK = *(const bf16x8*)(zn2 + row*LP_ + kc*32 + quad*8);
        aK[mt] = __builtin_amdgcn_mfma_f32_16x16x32_bf16(afK, bk[kc], aK[mt], 0, 0, 0);
        bf16x8 afO = *(const bf16x8*)(znp + row*128 + (((kc*4 + quad) ^ r7) << 3));
        aO[mt] = __builtin_amdgcn_mfma_f32_16x16x32_bf16(afO, bo[kc], aO[mt], 0, 0, 0);
      }
    }
    const float bO = bgo2[gcol], bK = blo2[gcol];
#pragma unroll
    for (int mt = 0; mt < 2; ++mt)
#pragma unroll
      for (int e = 0; e < 4; ++e){
        int grow = wm*32 + mt*16 + quad*4 + e;
        float s = sigm(aO[mt][e] + bO);
        out[(pos0 + grow)*D_ + gcol] = s*(aK[mt][e] + bK);
      }
  }
}

// ---------- v1 stageC (fallback) ----------
__global__ __launch_bounds__(256) void stageC_kernel(
    const u16* __restrict__ k_t, const float* __restrict__ z,
    const u16* __restrict__ wt, const float* __restrict__ bias2,
    float* __restrict__ out)
{
  __shared__ __align__(16) u16 zn2[64*LP_];
  __shared__ __align__(16) u16 kbuf[128*TP_];
  const u16* wtgo = wt + 4*16384;
  const u16* wtlo = wt + 5*16384;
  const float* bgo2 = bias2 + 4*128;
  const float* blo2 = bias2 + 5*128;
  const int bx = blockIdx.x;
  const int pos0 = (bx >> 3)*L_ + (bx & 7)*64;
  const int t = threadIdx.x, r = t >> 1, h = t & 1;
  const int rl4 = t >> 2, qd = t & 3;
  const int lane = t & 63, wave = t >> 6;
  const int quad = lane >> 4, l16 = lane & 15;
  const int wm = wave & 1, wn = wave >> 1;

#pragma unroll
  for (int q = 0; q < 4; ++q)
    *(uint4*)(kbuf + r*TP_ + h*32 + q*8) = *(const uint4*)(k_t + r*LL_ + pos0 + h*32 + q*8);
  __syncthreads();

  {
    float sum = 0.f, sq = 0.f;
    float kv[32];
#pragma unroll
    for (int q = 0; q < 32; ++q){
      union { unsigned int i; float f; } w;
      w.i = ((unsigned int)kbuf[(qd*32 + q)*TP_ + rl4]) << 16;
      kv[q] = w.f; sum += w.f; sq += w.f*w.f;
    }
    sum += __shfl_xor(sum, 1, 64); sq += __shfl_xor(sq, 1, 64);
    sum += __shfl_xor(sum, 2, 64); sq += __shfl_xor(sq, 2, 64);
    float mu = sum*(1.f/128.f);
    float rstd = rsqrtf(sq*(1.f/128.f) - mu*mu + 1e-5f);
#pragma unroll
    for (int q = 0; q < 4; ++q){
      U16x8 o;
#pragma unroll
      for (int e = 0; e < 8; ++e)
        o.s[e] = f2bf((kv[q*8+e] - mu)*rstd);
      *(uint4*)(zn2 + rl4*LP_ + qd*32 + q*8) = o.u4;
    }
  }
  __syncthreads();

  {
    const float* zr = z + (pos0 + rl4)*D_ + qd*32;
    float zv[32];
    float sum = 0.f, sq = 0.f;
#pragma unroll
    for (int q = 0; q < 8; ++q){
      float4 v = *(const float4*)(zr + q*4);
      zv[q*4+0] = v.x; zv[q*4+1] = v.y; zv[q*4+2] = v.z; zv[q*4+3] = v.w;
      sum += v.x + v.y + v.z + v.w;
      sq  += v.x*v.x + v.y*v.y + v.z*v.z + v.w*v.w;
    }
    sum += __shfl_xor(sum, 1, 64); sq += __shfl_xor(sq, 1, 64);
    sum += __shfl_xor(sum, 2, 64); sq += __shfl_xor(sq, 2, 64);
    float mu = sum*(1.f/128.f);
    float rstd = rsqrtf(sq*(1.f/128.f) - mu*mu + 1e-5f);
#pragma unroll
    for (int q = 0; q < 4; ++q){
      U16x8 o;
#pragma unroll
      for (int e = 0; e < 8; ++e)
        o.s[e] = f2bf((zv[q*8+e] - mu)*rstd);
      *(uint4*)(kbuf + rl4*LP_ + qd*32 + q*8) = o.u4;
    }
  }
  __syncthreads();

  f32x4 accK[2][4], accO[2][4];
  const f32x4 z4 = {0.f,0.f,0.f,0.f};
#pragma unroll
  for (int mt = 0; mt < 2; ++mt)
#pragma unroll
    for (int nt = 0; nt < 4; ++nt){ accK[mt][nt] = z4; accO[mt][nt] = z4; }

  gemm64(zn2,  wtlo, wm, wn, quad, l16, accK);
  gemm64(kbuf, wtgo, wm, wn, quad, l16, accO);

#pragma unroll
  for (int nt = 0; nt < 4; ++nt){
    int gcol = wn*64 + nt*16 + l16;
    float bo = bgo2[gcol], bl = blo2[gcol];
#pragma unroll
    for (int mt = 0; mt < 2; ++mt)
#pragma unroll
      for (int e = 0; e < 4; ++e){
        int grow = wm*32 + mt*16 + quad*4 + e;
        float s = sigm(accO[mt][nt][e] + bo);
        out[(pos0 + grow)*D_ + gcol] = s*(accK[mt][nt][e] + bl);
      }
  }
}

extern "C" void kernel_launch(void* const* d_in, const int* in_sizes, int n_in,
                              void* d_out, int out_size, void* d_ws, size_t ws_size,
                              hipStream_t stream)
{
  const float* z   = (const float*)d_in[0];
  const float* lnw = (const float*)d_in[1];
  const float* lnb = (const float*)d_in[2];
  const float* Wga = (const float*)d_in[3];
  const float* bga = (const float*)d_in[4];
  const float* Wla = (const float*)d_in[5];
  const float* bla = (const float*)d_in[6];
  const float* Wgb = (const float*)d_in[7];
  const float* bgb = (const float*)d_in[8];
  const float* Wlb = (const float*)d_in[9];
  const float* blb = (const float*)d_in[10];
  const float* onw = (const float*)d_in[11];
  const float* onb = (const float*)d_in[12];
  const float* Wgo = (const float*)d_in[13];
  const float* bgo = (const float*)d_in[14];
  const float* Wlo = (const float*)d_in[15];
  const float* blo = (const float*)d_in[16];

  u16* ws   = (u16*)d_ws;
  u16* wt   = ws + WT_OFF;
  float* b2 = (float*)(ws + B2_OFF);
  float* out = (float*)d_out;

  if (ws_size >= WS2_NEED_BYTES){
    u16* zn_g = ws + ZN_OFF;
    u16* a_t  = ws + AT2_OFF;
    u16* b_tt = ws + BT2_OFF;
    u16* k_t  = ws + KT2_OFF;
    convZ_kernel<<<2435, 256, 0, stream>>>(z, zn_g,
                                           Wga, Wla, Wgb, Wlb, Wgo, Wlo,
                                           lnw, lnb, onw, onb,
                                           bga, bla, bgb, blb, bgo, blo, wt, b2);
    stageA2_kernel<<<4096, 256, 0, stream>>>(zn_g, wt, b2, a_t, b_tt);
    stageT_kernel<<<2048, 256, 0, stream>>>(a_t, b_tt, k_t);
    stageC2_kernel<<<4096, 256, 0, stream>>>(k_t, zn_g, wt, b2, out);
  } else {
    u16* a_t  = ws + AT1_OFF;
    u16* b_tt = ws + BT1_OFF;
    u16* k_t  = ws + KT1_OFF;
    conv_kernel<<<387, 256, 0, stream>>>(Wga, Wla, Wgb, Wlb, Wgo, Wlo,
                                         lnw, lnb, onw, onb,
                                         bga, bla, bgb, blb, bgo, blo, wt, b2);
    stageA_kernel<<<4096, 256, 0, stream>>>(z, wt, b2, a_t, b_tt);
    stageT_kernel<<<2048, 256, 0, stream>>>(a_t, b_tt, k_t);
    stageC_kernel<<<4096, 256, 0, stream>>>(k_t, z, wt, b2, out);
  }
}

// Round 7
// 521.355 us; speedup vs baseline: 1.1282x; 1.0091x over previous
//
#include <hip/hip_runtime.h>

typedef unsigned short u16;
typedef __attribute__((ext_vector_type(8))) short bf16x8;
typedef __attribute__((ext_vector_type(4))) float f32x4;

#define L_ 512
#define D_ 128
#define LL_ (512*512)
#define LP_ 136   // LDS pitch for 128-wide rows (16B-aligned)
#define TP_ 72    // LDS pitch for 64-wide rows

// ---- workspace layouts (u16 elements) ----
#define WT_OFF 0
#define B2_OFF 98304            // 768 f32 = 1536 u16
#define ZN_OFF (B2_OFF + 1536)
#define AT2_OFF (ZN_OFF + 128*LL_)
#define BT2_OFF (AT2_OFF + 128*LL_)
#define KT2_OFF (BT2_OFF + 128*LL_)
#define WS2_NEED_BYTES ((size_t)(KT2_OFF + 128*LL_) * 2)
// v1 fallback layout
#define AT1_OFF (B2_OFF + 1536)
#define BT1_OFF (AT1_OFF + 128*LL_)
#define KT1_OFF (BT1_OFF + 128*LL_)

union U16x8 { uint4 u4; bf16x8 v; u16 s[8]; };
union U16x4 { ushort4 v; u16 s[4]; };

__device__ __forceinline__ u16 f2bf(float f){
  union { float f; unsigned int i; } w; w.f = f;
  unsigned int r = w.i + 0x7FFFu + ((w.i >> 16) & 1u);  // RNE
  return (u16)(r >> 16);
}
// packed bf16 convert: D = {bf16(hi)<<16 | bf16(lo)}, HW RNE (T12 recipe)
__device__ __forceinline__ unsigned cvtpk(float lo, float hi){
  unsigned r;
  asm("v_cvt_pk_bf16_f32 %0, %1, %2" : "=v"(r) : "v"(lo), "v"(hi));
  return r;
}
__device__ __forceinline__ float sigm(float x){
  // raw v_rcp_f32 (1 ulp) instead of full correctly-rounded div (~8 ops)
  return __builtin_amdgcn_rcpf(1.0f + __expf(-x));
}

// ---------- v2 prep: stageZ (blocks 0..2047) + weight transform (2048..2434) ----------
__global__ __launch_bounds__(256) void convZ_kernel(
    const float* __restrict__ z, u16* __restrict__ zn_g,
    const float* __restrict__ Wga, const float* __restrict__ Wla,
    const float* __restrict__ Wgb, const float* __restrict__ Wlb,
    const float* __restrict__ Wgo, const float* __restrict__ Wlo,
    const float* __restrict__ lnw, const float* __restrict__ lnb,
    const float* __restrict__ onw, const float* __restrict__ onb,
    const float* __restrict__ bga, const float* __restrict__ bla,
    const float* __restrict__ bgb, const float* __restrict__ blb,
    const float* __restrict__ bgo, const float* __restrict__ blo,
    u16* __restrict__ wt, float* __restrict__ bias2)
{
  if (blockIdx.x < 2048){
    // zn[pos][c] = (z[pos][c] - mu) * rstd  (bf16), once.
    const int t = threadIdx.x, r = t >> 1, h = t & 1;
    const int row = blockIdx.x*128 + r;
    const float* zrow = z + (long)row*D_ + h*64;
    float raw[64];
    float sum = 0.f, sq = 0.f;
#pragma unroll
    for (int q = 0; q < 16; ++q){
      float4 v = *(const float4*)(zrow + q*4);
      raw[q*4+0] = v.x; raw[q*4+1] = v.y; raw[q*4+2] = v.z; raw[q*4+3] = v.w;
      sum += v.x + v.y + v.z + v.w;
      sq  += v.x*v.x + v.y*v.y + v.z*v.z + v.w*v.w;
    }
    sum += __shfl_xor(sum, 1, 64);
    sq  += __shfl_xor(sq , 1, 64);
    float mu = sum * (1.f/128.f);
    float rstd = rsqrtf(sq*(1.f/128.f) - mu*mu + 1e-5f);
    u16* orow = zn_g + (long)row*D_ + h*64;
#pragma unroll
    for (int q = 0; q < 8; ++q){
      uint4 o;
      o.x = cvtpk((raw[q*8+0]-mu)*rstd, (raw[q*8+1]-mu)*rstd);
      o.y = cvtpk((raw[q*8+2]-mu)*rstd, (raw[q*8+3]-mu)*rstd);
      o.z = cvtpk((raw[q*8+4]-mu)*rstd, (raw[q*8+5]-mu)*rstd);
      o.w = cvtpk((raw[q*8+6]-mu)*rstd, (raw[q*8+7]-mu)*rstd);
      *(uint4*)(orow + q*8) = o;
    }
    return;
  }
  int vb = blockIdx.x - 2048;
  if (vb < 384){
    int idx = vb*256 + threadIdx.x;            // 0..98303
    int w = idx >> 14, rem = idx & 16383, n = rem >> 7, k = rem & 127;
    const float* src;
    switch (w){
      case 0: src = Wga; break; case 1: src = Wla; break; case 2: src = Wgb; break;
      case 3: src = Wlb; break; case 4: src = Wgo; break; default: src = Wlo;
    }
    float sc = (w == 5) ? onw[k] : lnw[k];
    wt[idx] = f2bf(src[k*128 + n] * sc);
  } else {
    int j = (vb - 384)*256 + threadIdx.x;      // 0..767
    if (j < 768){
      int w = j >> 7, n = j & 127;
      const float* src; const float* bs;
      switch (w){
        case 0: src = Wga; bs = bga; break; case 1: src = Wla; bs = bla; break;
        case 2: src = Wgb; bs = bgb; break; case 3: src = Wlb; bs = blb; break;
        case 4: src = Wgo; bs = bgo; break; default: src = Wlo; bs = blo;
      }
      const float* lb = (w == 5) ? onb : lnb;
      float acc = bs[n];
      for (int k = 0; k < 128; ++k) acc += lb[k] * src[k*128 + n];
      bias2[j] = acc;
    }
  }
}

// ---------- v1 prep (fallback) ----------
__global__ __launch_bounds__(256) void conv_kernel(
    const float* __restrict__ Wga, const float* __restrict__ Wla,
    const float* __restrict__ Wgb, const float* __restrict__ Wlb,
    const float* __restrict__ Wgo, const float* __restrict__ Wlo,
    const float* __restrict__ lnw, const float* __restrict__ lnb,
    const float* __restrict__ onw, const float* __restrict__ onb,
    const float* __restrict__ bga, const float* __restrict__ bla,
    const float* __restrict__ bgb, const float* __restrict__ blb,
    const float* __restrict__ bgo, const float* __restrict__ blo,
    u16* __restrict__ wt, float* __restrict__ bias2)
{
  if (blockIdx.x < 384){
    int idx = blockIdx.x*256 + threadIdx.x;
    int w = idx >> 14, rem = idx & 16383, n = rem >> 7, k = rem & 127;
    const float* src;
    switch (w){
      case 0: src = Wga; break; case 1: src = Wla; break; case 2: src = Wgb; break;
      case 3: src = Wlb; break; case 4: src = Wgo; break; default: src = Wlo;
    }
    float sc = (w == 5) ? onw[k] : lnw[k];
    wt[idx] = f2bf(src[k*128 + n] * sc);
  } else {
    int j = (blockIdx.x - 384)*256 + threadIdx.x;
    int w = j >> 7, n = j & 127;
    const float* src; const float* bs;
    switch (w){
      case 0: src = Wga; bs = bga; break; case 1: src = Wla; bs = bla; break;
      case 2: src = Wgb; bs = bgb; break; case 3: src = Wlb; bs = blb; break;
      case 4: src = Wgo; bs = bgo; break; default: src = Wlo; bs = blo;
    }
    const float* lb = (w == 5) ? onb : lnb;
    float acc = bs[n];
    for (int k = 0; k < 128; ++k) acc += lb[k] * src[k*128 + n];
    bias2[j] = acc;
  }
}

// gemm over pitched LDS (LP_) — v1 fallback
__device__ __forceinline__ void gemm128(const u16* znlds, const u16* __restrict__ wtm,
                                        int wm, int wn, int quad, int l16, f32x4 acc[4][4])
{
  bf16x8 bf[4][4];
#pragma unroll
  for (int nt = 0; nt < 4; ++nt){
    int n = wn*64 + nt*16 + l16;
#pragma unroll
    for (int kc = 0; kc < 4; ++kc){
      U16x8 u; u.u4 = *(const uint4*)(wtm + n*128 + kc*32 + quad*8);
      bf[nt][kc] = u.v;
    }
  }
#pragma unroll
  for (int mt = 0; mt < 4; ++mt){
    int row = wm*64 + mt*16 + l16;
    bf16x8 af[4];
#pragma unroll
    for (int kc = 0; kc < 4; ++kc)
      af[kc] = *(const bf16x8*)(znlds + row*LP_ + kc*32 + quad*8);
#pragma unroll
    for (int nt = 0; nt < 4; ++nt)
#pragma unroll
      for (int kc = 0; kc < 4; ++kc)
        acc[mt][nt] = __builtin_amdgcn_mfma_f32_16x16x32_bf16(af[kc], bf[nt][kc], acc[mt][nt], 0, 0, 0);
  }
}

__device__ __forceinline__ void gemm64(const u16* alds, const u16* __restrict__ wtm,
                                       int wm, int wn, int quad, int l16, f32x4 acc[2][4])
{
  bf16x8 bf[4][4];
#pragma unroll
  for (int nt = 0; nt < 4; ++nt){
    int n = wn*64 + nt*16 + l16;
#pragma unroll
    for (int kc = 0; kc < 4; ++kc){
      U16x8 u; u.u4 = *(const uint4*)(wtm + n*128 + kc*32 + quad*8);
      bf[nt][kc] = u.v;
    }
  }
#pragma unroll
  for (int mt = 0; mt < 2; ++mt){
    int row = wm*32 + mt*16 + l16;
    bf16x8 af[4];
#pragma unroll
    for (int kc = 0; kc < 4; ++kc)
      af[kc] = *(const bf16x8*)(alds + row*LP_ + kc*32 + quad*8);
#pragma unroll
    for (int nt = 0; nt < 4; ++nt)
#pragma unroll
      for (int kc = 0; kc < 4; ++kc)
        acc[mt][nt] = __builtin_amdgcn_mfma_f32_16x16x32_bf16(af[kc], bf[nt][kc], acc[mt][nt], 0, 0, 0);
  }
}

// ---------- v2 stageA: fused G/L gemm per N-tile, packed bf16 results ----------
__global__ __launch_bounds__(256) void stageA2_kernel(
    const u16* __restrict__ zn_g, const u16* __restrict__ wt,
    const float* __restrict__ bias2,
    u16* __restrict__ a_t, u16* __restrict__ b_tt)
{
  __shared__ __align__(16) u16 znS[128*128];   // 32 KiB; reused as trh after gemms

  const int bid = blockIdx.x;            // 4096 blocks, one 128-tile each
  const int type = bid >> 11;
  const int tile = bid & 2047;
  const int outer = tile >> 2;
  const int seg = tile & 3;

  const int t = threadIdx.x;
  const int r = t >> 1, h = t & 1;
  const int lane = t & 63, wave = t >> 6;
  const int quad = lane >> 4, l16 = lane & 15;
  const int wm = wave & 1, wn = wave >> 1;

  { // stage zn tile: LDS[row][cl] = zn_g[pos(row)][cl ^ (row&7)] (16B chunks)
    const int lr = lane >> 4, lc = lane & 15;
    const int r7s = (wave*4 + lr) & 7;
    const int cgx = lc ^ r7s;
#pragma unroll
    for (int q = 0; q < 8; ++q){
      int row = q*16 + wave*4 + lr;
      int gpos = (type == 0) ? (outer*L_ + seg*128 + row) : ((seg*128 + row)*L_ + outer);
      __builtin_amdgcn_global_load_lds(
          (const __attribute__((address_space(1))) void*)(zn_g + (long)gpos*D_ + cgx*8),
          (__attribute__((address_space(3))) void*)(&znS[(q*16 + wave*4)*128]),
          16, 0, 0);
    }
  }
  __syncthreads();

  const u16* wg   = wt + (type ? 2 : 0)*16384;
  const u16* wl   = wt + (type ? 3 : 1)*16384;
  const float* bgp = bias2 + (type ? 2 : 0)*128;
  const float* blp = bias2 + (type ? 3 : 1)*128;
  const int r7 = l16 & 7;

  // fused per-nt: both gemms share each A-fragment; results packed to bf16 u32 pairs
  unsigned int pk[4][4][2];
#pragma unroll
  for (int nt = 0; nt < 4; ++nt){
    const int n = wn*64 + nt*16 + l16;
    bf16x8 bg[4], blw[4];
#pragma unroll
    for (int kc = 0; kc < 4; ++kc){
      U16x8 u; u.u4 = *(const uint4*)(wg + n*128 + kc*32 + quad*8); bg[kc]  = u.v;
      U16x8 v; v.u4 = *(const uint4*)(wl + n*128 + kc*32 + quad*8); blw[kc] = v.v;
    }
    f32x4 aG[4], aL[4];
#pragma unroll
    for (int mt = 0; mt < 4; ++mt){
      aG[mt] = (f32x4){0.f,0.f,0.f,0.f};
      aL[mt] = (f32x4){0.f,0.f,0.f,0.f};
    }
#pragma unroll
    for (int mt = 0; mt < 4; ++mt){
      const int row = wm*64 + mt*16 + l16;
#pragma unroll
      for (int kc = 0; kc < 4; ++kc){
        bf16x8 af = *(const bf16x8*)(znS + row*128 + (((kc*4 + quad) ^ r7) << 3));
        aG[mt] = __builtin_amdgcn_mfma_f32_16x16x32_bf16(af, bg[kc],  aG[mt], 0, 0, 0);
        aL[mt] = __builtin_amdgcn_mfma_f32_16x16x32_bf16(af, blw[kc], aL[mt], 0, 0, 0);
      }
    }
    const float bbG = bgp[n], bbL = blp[n];
#pragma unroll
    for (int mt = 0; mt < 4; ++mt){
      float v0 = sigm(aG[mt][0] + bbG) * (aL[mt][0] + bbL);
      float v1 = sigm(aG[mt][1] + bbG) * (aL[mt][1] + bbL);
      float v2 = sigm(aG[mt][2] + bbG) * (aL[mt][2] + bbL);
      float v3 = sigm(aG[mt][3] + bbG) * (aL[mt][3] + bbL);
      pk[nt][mt][0] = cvtpk(v0, v1);
      pk[nt][mt][1] = cvtpk(v2, v3);
    }
  }

  __syncthreads();   // all LDS reads of znS done; reuse as trh

  u16* trh = znS;
  u16* dst = type ? b_tt : a_t;
  const int base = outer*L_ + seg*128;
#pragma unroll
  for (int pass = 0; pass < 2; ++pass){
    if (wm == pass){
#pragma unroll
      for (int nt = 0; nt < 4; ++nt){
        int gcol = wn*64 + nt*16 + l16;
#pragma unroll
        for (int mt = 0; mt < 4; ++mt){
          uint2 w2; w2.x = pk[nt][mt][0]; w2.y = pk[nt][mt][1];
          *(uint2*)(trh + gcol*TP_ + mt*16 + quad*4) = w2;
        }
      }
    }
    __syncthreads();
#pragma unroll
    for (int q = 0; q < 4; ++q){
      uint4 v = *(const uint4*)(trh + r*TP_ + h*32 + q*8);
      *(uint4*)(dst + r*LL_ + base + pass*64 + h*32 + q*8) = v;
    }
    __syncthreads();
  }
}

// ---------- v1 stageA (fallback, LN inline) ----------
__global__ __launch_bounds__(256) void stageA_kernel(
    const float* __restrict__ z, const u16* __restrict__ wt,
    const float* __restrict__ bias2,
    u16* __restrict__ a_t, u16* __restrict__ b_tt)
{
  __shared__ __align__(16) u16 smem[128*LP_];
  u16* zn = smem;
  u16* trh = smem;

  const int bid = blockIdx.x;
  const int type = bid >> 11;
  const int tile = bid & 2047;
  const int outer = tile >> 2;
  const int seg = tile & 3;

  const int t = threadIdx.x;
  const int r = t >> 1, h = t & 1;
  const int lane = t & 63, wave = t >> 6;
  const int quad = lane >> 4, l16 = lane & 15;
  const int wm = wave & 1, wn = wave >> 1;

  {
    int gpos = (type == 0) ? (outer*L_ + seg*128 + r) : ((seg*128 + r)*L_ + outer);
    const float* zrow = z + gpos*D_ + h*64;
    float raw[64];
    float sum = 0.f, sq = 0.f;
#pragma unroll
    for (int q = 0; q < 16; ++q){
      float4 v = *(const float4*)(zrow + q*4);
      raw[q*4+0] = v.x; raw[q*4+1] = v.y; raw[q*4+2] = v.z; raw[q*4+3] = v.w;
      sum += v.x + v.y + v.z + v.w;
      sq  += v.x*v.x + v.y*v.y + v.z*v.z + v.w*v.w;
    }
    sum += __shfl_xor(sum, 1, 64);
    sq  += __shfl_xor(sq , 1, 64);
    float mu = sum * (1.f/128.f);
    float rstd = rsqrtf(sq*(1.f/128.f) - mu*mu + 1e-5f);
#pragma unroll
    for (int q = 0; q < 8; ++q){
      U16x8 o;
#pragma unroll
      for (int e = 0; e < 8; ++e)
        o.s[e] = f2bf((raw[q*8+e] - mu)*rstd);
      *(uint4*)(zn + r*LP_ + h*64 + q*8) = o.u4;
    }
  }
  __syncthreads();

  const u16* wg   = wt + (type ? 2 : 0)*16384;
  const u16* wl   = wt + (type ? 3 : 1)*16384;
  const float* bgp = bias2 + (type ? 2 : 0)*128;
  const float* blp = bias2 + (type ? 3 : 1)*128;
  const f32x4 z4 = {0.f, 0.f, 0.f, 0.f};

  f32x4 accG[4][4], accL[4][4];
#pragma unroll
  for (int mt = 0; mt < 4; ++mt)
#pragma unroll
    for (int nt = 0; nt < 4; ++nt){ accG[mt][nt] = z4; accL[mt][nt] = z4; }

  gemm128(zn, wg, wm, wn, quad, l16, accG);
#pragma unroll
  for (int nt = 0; nt < 4; ++nt){
    float bb = bgp[wn*64 + nt*16 + l16];
#pragma unroll
    for (int mt = 0; mt < 4; ++mt)
#pragma unroll
      for (int e = 0; e < 4; ++e)
        accG[mt][nt][e] = sigm(accG[mt][nt][e] + bb);
  }
  gemm128(zn, wl, wm, wn, quad, l16, accL);
#pragma unroll
  for (int nt = 0; nt < 4; ++nt){
    float bb = blp[wn*64 + nt*16 + l16];
#pragma unroll
    for (int mt = 0; mt < 4; ++mt)
#pragma unroll
      for (int e = 0; e < 4; ++e)
        accG[mt][nt][e] *= (accL[mt][nt][e] + bb);
  }

  __syncthreads();

  u16* dst = type ? b_tt : a_t;
  const int base = outer*L_ + seg*128;
#pragma unroll
  for (int pass = 0; pass < 2; ++pass){
    if (wm == pass){
#pragma unroll
      for (int nt = 0; nt < 4; ++nt){
        int gcol = wn*64 + nt*16 + l16;
#pragma unroll
        for (int mt = 0; mt < 4; ++mt){
          U16x4 pk4;
#pragma unroll
          for (int e = 0; e < 4; ++e)
            pk4.s[e] = f2bf(accG[mt][nt][e]);
          *(ushort4*)(trh + gcol*TP_ + mt*16 + quad*4) = pk4.v;
        }
      }
    }
    __syncthreads();
#pragma unroll
    for (int q = 0; q < 4; ++q){
      uint4 v = *(const uint4*)(trh + r*TP_ + h*32 + q*8);
      *(uint4*)(dst + r*LL_ + base + pass*64 + h*32 + q*8) = v;
    }
    __syncthreads();
  }
}

// k_t[c][i][j] = sum_m a_t[c][i][m] * b_tt[c][j][m]
// r4-verified: single-buffer 32 KB, global_load_lds w16 + XOR swizzle, XCD-swizzled grid.
__global__ __launch_bounds__(256) void stageT_kernel(
    const u16* __restrict__ a_t, const u16* __restrict__ b_tt, u16* __restrict__ k_t)
{
  __shared__ __align__(16) u16 As[128*64];   // 16 KiB
  __shared__ __align__(16) u16 Bs[128*64];   // 16 KiB
  const int bid = blockIdx.x;                 // 2048 = 8 * 256
  const int lid = (bid & 7)*256 + (bid >> 3); // XCD k owns 16 whole channels
  const int c = lid >> 4, it = (lid >> 2) & 3, jt = lid & 3;
  const u16* Ab = a_t + c*LL_ + it*128*L_;
  const u16* Bb = b_tt + c*LL_ + jt*128*L_;
  const int t = threadIdx.x;
  const int lane = t & 63, wave = t >> 6;
  const int quad = lane >> 4, l16 = lane & 15;
  const int wm = wave & 1, wn = wave >> 1;
  const int sr8 = lane >> 3, scl = lane & 7;
  const int cgx = scl ^ sr8;
  const int swz = (l16 & 7) << 3;

  f32x4 acc[4][4];
  const f32x4 z4 = {0.f,0.f,0.f,0.f};
#pragma unroll
  for (int mt = 0; mt < 4; ++mt)
#pragma unroll
    for (int nt = 0; nt < 4; ++nt) acc[mt][nt] = z4;

  for (int kt = 0; kt < 8; ++kt){
    const int k0 = kt*64;
#pragma unroll
    for (int q = 0; q < 4; ++q){
      int row = q*32 + wave*8 + sr8;
      __builtin_amdgcn_global_load_lds(
          (const __attribute__((address_space(1))) void*)(Ab + row*L_ + k0 + cgx*8),
          (__attribute__((address_space(3))) void*)(&As[(q*32 + wave*8)*64]),
          16, 0, 0);
    }
#pragma unroll
    for (int q = 0; q < 4; ++q){
      int row = q*32 + wave*8 + sr8;
      __builtin_amdgcn_global_load_lds(
          (const __attribute__((address_space(1))) void*)(Bb + row*L_ + k0 + cgx*8),
          (__attribute__((address_space(3))) void*)(&Bs[(q*32 + wave*8)*64]),
          16, 0, 0);
    }
    __syncthreads();
    bf16x8 bfr[4][2];
#pragma unroll
    for (int nt = 0; nt < 4; ++nt){
      int brow = wn*64 + nt*16 + l16;
#pragma unroll
      for (int ks = 0; ks < 2; ++ks)
        bfr[nt][ks] = *(const bf16x8*)(Bs + brow*64 + (((ks*4 + quad)*8) ^ swz));
    }
#pragma unroll
    for (int mt = 0; mt < 4; ++mt){
      int arow = wm*64 + mt*16 + l16;
      bf16x8 af[2];
#pragma unroll
      for (int ks = 0; ks < 2; ++ks)
        af[ks] = *(const bf16x8*)(As + arow*64 + (((ks*4 + quad)*8) ^ swz));
#pragma unroll
      for (int nt = 0; nt < 4; ++nt)
#pragma unroll
        for (int ks = 0; ks < 2; ++ks)
          acc[mt][nt] = __builtin_amdgcn_mfma_f32_16x16x32_bf16(af[ks], bfr[nt][ks], acc[mt][nt], 0, 0, 0);
    }
    __syncthreads();
  }

#pragma unroll
  for (int mt = 0; mt < 4; ++mt)
#pragma unroll
    for (int nt = 0; nt < 4; ++nt){
      int gcol = wn*64 + nt*16 + l16;
      u16* kp = k_t + c*LL_ + (it*128 + wm*64 + mt*16 + quad*4)*L_ + jt*128 + gcol;
#pragma unroll
      for (int e = 0; e < 4; e += 2){
        unsigned p = cvtpk(acc[mt][nt][e], acc[mt][nt][e+1]);
        kp[e*L_]       = (u16)p;          // store_short
        kp[(e+1)*L_]   = (u16)(p >> 16);  // store_short_d16_hi
      }
    }
}

// ---------- v2 stageC: async staging + fused K/O gemms per N-tile ----------
__global__ __launch_bounds__(256) void stageC2_kernel(
    const u16* __restrict__ k_t, const u16* __restrict__ zn_g,
    const u16* __restrict__ wt, const float* __restrict__ bias2,
    float* __restrict__ out)
{
  __shared__ __align__(16) u16 kl[128*64];    // k tile [c][j] linear (16 KB)
  __shared__ __align__(16) u16 znp[64*128];   // zn rows, XOR-swizzled linear (16 KB)
  __shared__ __align__(16) u16 zn2[64*LP_];   // LN_c(k) [j][c] pitched (17 KB)
  const u16* wtgo = wt + 4*16384;
  const u16* wtlo = wt + 5*16384;
  const float* bgo2 = bias2 + 4*128;
  const float* blo2 = bias2 + 5*128;
  const int bx = blockIdx.x;
  const int pos0 = (bx >> 3)*L_ + (bx & 7)*64;
  const int t = threadIdx.x;
  const int rl4 = t >> 2, qd = t & 3;
  const int lane = t & 63, wave = t >> 6;
  const int quad = lane >> 4, l16 = lane & 15;
  const int wm = wave & 1, wn = wave >> 1;

  // issue k-tile loads: idx -> c = idx>>3, ch = idx&7 (16B chunks)
#pragma unroll
  for (int q = 0; q < 4; ++q){
    int base = q*256 + wave*64;
    int idx = base + lane;
    int c = idx >> 3, ch = idx & 7;
    __builtin_amdgcn_global_load_lds(
        (const __attribute__((address_space(1))) void*)(k_t + (long)c*LL_ + pos0 + ch*8),
        (__attribute__((address_space(3))) void*)(&kl[base*8]),
        16, 0, 0);
  }
  // issue zn-row loads: idx -> j = idx>>4, ch = idx&15; src chunk pre-swizzled
#pragma unroll
  for (int q = 0; q < 4; ++q){
    int base = q*256 + wave*64;
    int idx = base + lane;
    int j = idx >> 4, ch = idx & 15;
    int chx = ch ^ (j & 7);
    __builtin_amdgcn_global_load_lds(
        (const __attribute__((address_space(1))) void*)(zn_g + (long)(pos0 + j)*D_ + chx*8),
        (__attribute__((address_space(3))) void*)(&znp[base*8]),
        16, 0, 0);
  }
  asm volatile("s_waitcnt vmcnt(4)" ::: "memory");   // k-tile resident (zn in flight)
  __builtin_amdgcn_s_barrier();
  asm volatile("" ::: "memory");

  { // LN over channels of k for column j=rl4 (4 threads/column via qd)
    float sum = 0.f, sq = 0.f;
    float kv[32];
#pragma unroll
    for (int q = 0; q < 32; ++q){
      union { unsigned int i; float f; } w;
      w.i = ((unsigned int)kl[(qd*32 + q)*64 + rl4]) << 16;
      kv[q] = w.f; sum += w.f; sq += w.f*w.f;
    }
    sum += __shfl_xor(sum, 1, 64); sq += __shfl_xor(sq, 1, 64);
    sum += __shfl_xor(sum, 2, 64); sq += __shfl_xor(sq, 2, 64);
    float mu = sum*(1.f/128.f);
    float rstd = rsqrtf(sq*(1.f/128.f) - mu*mu + 1e-5f);
#pragma unroll
    for (int q = 0; q < 4; ++q){
      uint4 o;
      o.x = cvtpk((kv[q*8+0]-mu)*rstd, (kv[q*8+1]-mu)*rstd);
      o.y = cvtpk((kv[q*8+2]-mu)*rstd, (kv[q*8+3]-mu)*rstd);
      o.z = cvtpk((kv[q*8+4]-mu)*rstd, (kv[q*8+5]-mu)*rstd);
      o.w = cvtpk((kv[q*8+6]-mu)*rstd, (kv[q*8+7]-mu)*rstd);
      *(uint4*)(zn2 + rl4*LP_ + qd*32 + q*8) = o;
    }
  }
  __syncthreads();   // zn2 visible; znp loads drained (full vmcnt drain at barrier)

  const int r7 = l16 & 7;
#pragma unroll
  for (int nt = 0; nt < 4; ++nt){
    const int gcol = wn*64 + nt*16 + l16;
    bf16x8 bk[4], bo[4];
#pragma unroll
    for (int kc = 0; kc < 4; ++kc){
      U16x8 u; u.u4 = *(const uint4*)(wtlo + gcol*128 + kc*32 + quad*8); bk[kc] = u.v;
      U16x8 v; v.u4 = *(const uint4*)(wtgo + gcol*128 + kc*32 + quad*8); bo[kc] = v.v;
    }
    f32x4 aK[2], aO[2];
#pragma unroll
    for (int mt = 0; mt < 2; ++mt){
      aK[mt] = (f32x4){0.f,0.f,0.f,0.f};
      aO[mt] = (f32x4){0.f,0.f,0.f,0.f};
    }
#pragma unroll
    for (int mt = 0; mt < 2; ++mt){
      const int row = wm*32 + mt*16 + l16;
#pragma unroll
      for (int kc = 0; kc < 4; ++kc){
        bf16x8 afK = *(const bf16x8*)(zn2 + row*LP_ + kc*32 + quad*8);
        aK[mt] = __builtin_amdgcn_mfma_f32_16x16x32_bf16(afK, bk[kc], aK[mt], 0, 0, 0);
        bf16x8 afO = *(const bf16x8*)(znp + row*128 + (((kc*4 + quad) ^ r7) << 3));
        aO[mt] = __builtin_amdgcn_mfma_f32_16x16x32_bf16(afO, bo[kc], aO[mt], 0, 0, 0);
      }
    }
    const float bO = bgo2[gcol], bK = blo2[gcol];
#pragma unroll
    for (int mt = 0; mt < 2; ++mt)
#pragma unroll
      for (int e = 0; e < 4; ++e){
        int grow = wm*32 + mt*16 + quad*4 + e;
        float s = sigm(aO[mt][e] + bO);
        out[(pos0 + grow)*D_ + gcol] = s*(aK[mt][e] + bK);
      }
  }
}

// ---------- v1 stageC (fallback) ----------
__global__ __launch_bounds__(256) void stageC_kernel(
    const u16* __restrict__ k_t, const float* __restrict__ z,
    const u16* __restrict__ wt, const float* __restrict__ bias2,
    float* __restrict__ out)
{
  __shared__ __align__(16) u16 zn2[64*LP_];
  __shared__ __align__(16) u16 kbuf[128*TP_];
  const u16* wtgo = wt + 4*16384;
  const u16* wtlo = wt + 5*16384;
  const float* bgo2 = bias2 + 4*128;
  const float* blo2 = bias2 + 5*128;
  const int bx = blockIdx.x;
  const int pos0 = (bx >> 3)*L_ + (bx & 7)*64;
  const int t = threadIdx.x, r = t >> 1, h = t & 1;
  const int rl4 = t >> 2, qd = t & 3;
  const int lane = t & 63, wave = t >> 6;
  const int quad = lane >> 4, l16 = lane & 15;
  const int wm = wave & 1, wn = wave >> 1;

#pragma unroll
  for (int q = 0; q < 4; ++q)
    *(uint4*)(kbuf + r*TP_ + h*32 + q*8) = *(const uint4*)(k_t + r*LL_ + pos0 + h*32 + q*8);
  __syncthreads();

  {
    float sum = 0.f, sq = 0.f;
    float kv[32];
#pragma unroll
    for (int q = 0; q < 32; ++q){
      union { unsigned int i; float f; } w;
      w.i = ((unsigned int)kbuf[(qd*32 + q)*TP_ + rl4]) << 16;
      kv[q] = w.f; sum += w.f; sq += w.f*w.f;
    }
    sum += __shfl_xor(sum, 1, 64); sq += __shfl_xor(sq, 1, 64);
    sum += __shfl_xor(sum, 2, 64); sq += __shfl_xor(sq, 2, 64);
    float mu = sum*(1.f/128.f);
    float rstd = rsqrtf(sq*(1.f/128.f) - mu*mu + 1e-5f);
#pragma unroll
    for (int q = 0; q < 4; ++q){
      U16x8 o;
#pragma unroll
      for (int e = 0; e < 8; ++e)
        o.s[e] = f2bf((kv[q*8+e] - mu)*rstd);
      *(uint4*)(zn2 + rl4*LP_ + qd*32 + q*8) = o.u4;
    }
  }
  __syncthreads();

  {
    const float* zr = z + (pos0 + rl4)*D_ + qd*32;
    float zv[32];
    float sum = 0.f, sq = 0.f;
#pragma unroll
    for (int q = 0; q < 8; ++q){
      float4 v = *(const float4*)(zr + q*4);
      zv[q*4+0] = v.x; zv[q*4+1] = v.y; zv[q*4+2] = v.z; zv[q*4+3] = v.w;
      sum += v.x + v.y + v.z + v.w;
      sq  += v.x*v.x + v.y*v.y + v.z*v.z + v.w*v.w;
    }
    sum += __shfl_xor(sum, 1, 64); sq += __shfl_xor(sq, 1, 64);
    sum += __shfl_xor(sum, 2, 64); sq += __shfl_xor(sq, 2, 64);
    float mu = sum*(1.f/128.f);
    float rstd = rsqrtf(sq*(1.f/128.f) - mu*mu + 1e-5f);
#pragma unroll
    for (int q = 0; q < 4; ++q){
      U16x8 o;
#pragma unroll
      for (int e = 0; e < 8; ++e)
        o.s[e] = f2bf((zv[q*8+e] - mu)*rstd);
      *(uint4*)(kbuf + rl4*LP_ + qd*32 + q*8) = o.u4;
    }
  }
  __syncthreads();

  f32x4 accK[2][4], accO[2][4];
  const f32x4 z4 = {0.f,0.f,0.f,0.f};
#pragma unroll
  for (int mt = 0; mt < 2; ++mt)
#pragma unroll
    for (int nt = 0; nt < 4; ++nt){ accK[mt][nt] = z4; accO[mt][nt] = z4; }

  gemm64(zn2,  wtlo, wm, wn, quad, l16, accK);
  gemm64(kbuf, wtgo, wm, wn, quad, l16, accO);

#pragma unroll
  for (int nt = 0; nt < 4; ++nt){
    int gcol = wn*64 + nt*16 + l16;
    float bo = bgo2[gcol], bl = blo2[gcol];
#pragma unroll
    for (int mt = 0; mt < 2; ++mt)
#pragma unroll
      for (int e = 0; e < 4; ++e){
        int grow = wm*32 + mt*16 + quad*4 + e;
        float s = sigm(accO[mt][nt][e] + bo);
        out[(pos0 + grow)*D_ + gcol] = s*(accK[mt][nt][e] + bl);
      }
  }
}

extern "C" void kernel_launch(void* const* d_in, const int* in_sizes, int n_in,
                              void* d_out, int out_size, void* d_ws, size_t ws_size,
                              hipStream_t stream)
{
  const float* z   = (const float*)d_in[0];
  const float* lnw = (const float*)d_in[1];
  const float* lnb = (const float*)d_in[2];
  const float* Wga = (const float*)d_in[3];
  const float* bga = (const float*)d_in[4];
  const float* Wla = (const float*)d_in[5];
  const float* bla = (const float*)d_in[6];
  const float* Wgb = (const float*)d_in[7];
  const float* bgb = (const float*)d_in[8];
  const float* Wlb = (const float*)d_in[9];
  const float* blb = (const float*)d_in[10];
  const float* onw = (const float*)d_in[11];
  const float* onb = (const float*)d_in[12];
  const float* Wgo = (const float*)d_in[13];
  const float* bgo = (const float*)d_in[14];
  const float* Wlo = (const float*)d_in[15];
  const float* blo = (const float*)d_in[16];

  u16* ws   = (u16*)d_ws;
  u16* wt   = ws + WT_OFF;
  float* b2 = (float*)(ws + B2_OFF);
  float* out = (float*)d_out;

  if (ws_size >= WS2_NEED_BYTES){
    u16* zn_g = ws + ZN_OFF;
    u16* a_t  = ws + AT2_OFF;
    u16* b_tt = ws + BT2_OFF;
    u16* k_t  = ws + KT2_OFF;
    convZ_kernel<<<2435, 256, 0, stream>>>(z, zn_g,
                                           Wga, Wla, Wgb, Wlb, Wgo, Wlo,
                                           lnw, lnb, onw, onb,
                                           bga, bla, bgb, blb, bgo, blo, wt, b2);
    stageA2_kernel<<<4096, 256, 0, stream>>>(zn_g, wt, b2, a_t, b_tt);
    stageT_kernel<<<2048, 256, 0, stream>>>(a_t, b_tt, k_t);
    stageC2_kernel<<<4096, 256, 0, stream>>>(k_t, zn_g, wt, b2, out);
  } else {
    u16* a_t  = ws + AT1_OFF;
    u16* b_tt = ws + BT1_OFF;
    u16* k_t  = ws + KT1_OFF;
    conv_kernel<<<387, 256, 0, stream>>>(Wga, Wla, Wgb, Wlb, Wgo, Wlo,
                                         lnw, lnb, onw, onb,
                                         bga, bla, bgb, blb, bgo, blo, wt, b2);
    stageA_kernel<<<4096, 256, 0, stream>>>(z, wt, b2, a_t, b_tt);
    stageT_kernel<<<2048, 256, 0, stream>>>(a_t, b_tt, k_t);
    stageC_kernel<<<4096, 256, 0, stream>>>(k_t, z, wt, b2, out);
  }
}